// Round 5
// baseline (452.049 us; speedup 1.0000x reference)
//
#include <hip/hip_runtime.h>
#include <hip/hip_bf16.h>

typedef unsigned short u16;
typedef __attribute__((ext_vector_type(4))) unsigned short u16x4;
typedef __attribute__((ext_vector_type(8))) unsigned short u16x8;
typedef __attribute__((ext_vector_type(8))) short bf16x8;
typedef __attribute__((ext_vector_type(4))) float f32x4;

__device__ __forceinline__ float b2f(u16 v) {
    return __uint_as_float(((unsigned)v) << 16);
}
__device__ __forceinline__ u16 f2bf(float f) {
    unsigned u = __float_as_uint(f);
    unsigned r = (u + 0x7fffu + ((u >> 16) & 1u)) >> 16;
    return (u16)r;
}

// ---------------------------------------------------------------------------
// Mask normalize: detect {bool8, int32, float32} encoding, write uint8[2048].
// Byte classes mod 4 over first 2048 bytes (= batch 0 in all encodings):
//   bool8 : nonzero bytes at class 1 (and all classes)
//   int32 : only class 0 nonzero (LSB of 1)
//   float32: only classes 2,3 nonzero (1.0f = 00 00 80 3F)
// ---------------------------------------------------------------------------
__global__ void prep_mask(const unsigned char* __restrict__ mb,
                          unsigned char* __restrict__ mout, int n) {
    __shared__ int c0s, c1s;
    if (threadIdx.x == 0) { c0s = 0; c1s = 0; }
    __syncthreads();
    int a0 = 0, a1 = 0;
    for (int i = threadIdx.x; i < 2048; i += 256) {
        if (mb[i]) {
            int cl = i & 3;
            if (cl == 0) a0 = 1;
            else if (cl == 1) a1 = 1;
        }
    }
    if (a0) atomicOr(&c0s, 1);
    if (a1) atomicOr(&c1s, 1);
    __syncthreads();
    int fmt = c1s ? 1 : (c0s ? 0 : 2);  // 1=bool8, 0=int32, 2=float32
    for (int e = threadIdx.x; e < n; e += 256) {
        unsigned char v;
        if (fmt == 1)      v = (mb[e] != 0);
        else if (fmt == 0) v = (((const int*)mb)[e] != 0);
        else               v = (((const float*)mb)[e] != 0.f);
        mout[e] = v;
    }
}

// ---------------------------------------------------------------------------
// f32 -> bf16 convert, 8 elems/thread.
// ---------------------------------------------------------------------------
__global__ __launch_bounds__(256) void cvt_kernel(const float* __restrict__ in,
                                                  u16* __restrict__ out, int n8) {
    int i = blockIdx.x * 256 + threadIdx.x;
    if (i >= n8) return;
    float4 a = ((const float4*)in)[i * 2];
    float4 b = ((const float4*)in)[i * 2 + 1];
    u16x8 o;
    o[0] = f2bf(a.x); o[1] = f2bf(a.y); o[2] = f2bf(a.z); o[3] = f2bf(a.w);
    o[4] = f2bf(b.x); o[5] = f2bf(b.y); o[6] = f2bf(b.z); o[7] = f2bf(b.w);
    ((u16x8*)out)[i] = o;
}

// ---------------------------------------------------------------------------
// LayerNorm: 8192 rows x 1024 f32 in, bf16 out. One wave per row, 4 rows/block.
// ---------------------------------------------------------------------------
__global__ __launch_bounds__(256) void ln_kernel(const float* __restrict__ x,
                                                 const float* __restrict__ g,
                                                 const float* __restrict__ bta,
                                                 u16* __restrict__ y) {
    const int lane = threadIdx.x & 63;
    const int row = blockIdx.x * 4 + (threadIdx.x >> 6);
    const float* xr = x + (size_t)row * 1024;
    float v[16];
    float sum = 0.f, sq = 0.f;
#pragma unroll
    for (int c = 0; c < 4; ++c) {
        float4 u = ((const float4*)xr)[c * 64 + lane];
        v[c * 4 + 0] = u.x; v[c * 4 + 1] = u.y; v[c * 4 + 2] = u.z; v[c * 4 + 3] = u.w;
        sum += u.x + u.y + u.z + u.w;
        sq += u.x * u.x + u.y * u.y + u.z * u.z + u.w * u.w;
    }
#pragma unroll
    for (int o = 1; o < 64; o <<= 1) {
        sum += __shfl_xor(sum, o, 64);
        sq += __shfl_xor(sq, o, 64);
    }
    float mean = sum * (1.f / 1024.f);
    float var = sq * (1.f / 1024.f) - mean * mean;
    float rs = rsqrtf(var + 1e-5f);
    u16* yr = y + (size_t)row * 1024;
#pragma unroll
    for (int c = 0; c < 4; ++c) {
        float4 ug = ((const float4*)g)[c * 64 + lane];
        float4 ub = ((const float4*)bta)[c * 64 + lane];
        u16x4 o;
        o[0] = f2bf((v[c * 4 + 0] - mean) * rs * ug.x + ub.x);
        o[1] = f2bf((v[c * 4 + 1] - mean) * rs * ug.y + ub.y);
        o[2] = f2bf((v[c * 4 + 2] - mean) * rs * ug.z + ub.z);
        o[3] = f2bf((v[c * 4 + 3] - mean) * rs * ug.w + ub.w);
        *(u16x4*)(yr + c * 256 + lane * 4) = o;
    }
}

// ---------------------------------------------------------------------------
// Generic bf16 GEMM: C(MxN) = A(MxK) @ B(KxN), A,B row-major bf16.
// C output: bf16 (OUTF32=0) or f32 (OUTF32=1).
// 128x128 tile, BK=32, 256 threads = 4 waves (2x2), mfma_f32_16x16x32_bf16.
// ---------------------------------------------------------------------------
template <int OUTF32>
__global__ __launch_bounds__(256, 2) void gemm_nn(const u16* __restrict__ A,
                                                  const u16* __restrict__ B,
                                                  void* __restrict__ Cv,
                                                  int M, int N, int K) {
    __shared__ u16 As[128][40];  // [row][k], +8 pad
    __shared__ u16 Bs[128][40];  // [col][k], +8 pad (transposed B)
    const int tid = threadIdx.x;
    const int lane = tid & 63;
    const int w = tid >> 6;
    const int wm = w >> 1, wn = w & 1;
    const int l15 = lane & 15, l4 = lane >> 4;
    const int row0 = blockIdx.y * 128;
    const int col0 = blockIdx.x * 128;

    f32x4 zero = {0.f, 0.f, 0.f, 0.f};
    f32x4 acc[4][4];
#pragma unroll
    for (int i = 0; i < 4; ++i)
#pragma unroll
        for (int j = 0; j < 4; ++j) acc[i][j] = zero;

    const int ar = tid >> 2, ak = (tid & 3) * 8;
    const int bk = tid >> 4, bc = (tid & 15) * 8;

    for (int k0 = 0; k0 < K; k0 += 32) {
        __syncthreads();
#pragma unroll
        for (int p = 0; p < 2; ++p) {
            int r = ar + p * 64;
            u16x8 va = *(const u16x8*)(A + (size_t)(row0 + r) * K + (k0 + ak));
            *(u16x8*)(&As[r][ak]) = va;
        }
#pragma unroll
        for (int p = 0; p < 2; ++p) {
            int kk = bk + p * 16;
            u16x8 vb = *(const u16x8*)(B + (size_t)(k0 + kk) * N + (col0 + bc));
#pragma unroll
            for (int i = 0; i < 8; ++i) Bs[bc + i][kk] = vb[i];
        }
        __syncthreads();
        bf16x8 aF[4], bF[4];
#pragma unroll
        for (int m = 0; m < 4; ++m)
            aF[m] = *(const bf16x8*)(&As[wm * 64 + m * 16 + l15][l4 * 8]);
#pragma unroll
        for (int n = 0; n < 4; ++n)
            bF[n] = *(const bf16x8*)(&Bs[wn * 64 + n * 16 + l15][l4 * 8]);
#pragma unroll
        for (int m = 0; m < 4; ++m)
#pragma unroll
            for (int n = 0; n < 4; ++n)
                acc[m][n] = __builtin_amdgcn_mfma_f32_16x16x32_bf16(aF[m], bF[n], acc[m][n], 0, 0, 0);
    }
#pragma unroll
    for (int m = 0; m < 4; ++m)
#pragma unroll
        for (int n = 0; n < 4; ++n) {
            int row = row0 + wm * 64 + m * 16 + l4 * 4;
            int col = col0 + wn * 64 + n * 16 + l15;
#pragma unroll
            for (int r = 0; r < 4; ++r) {
                if (OUTF32)
                    ((float*)Cv)[(size_t)(row + r) * N + col] = acc[m][n][r];
                else
                    ((u16*)Cv)[(size_t)(row + r) * N + col] = f2bf(acc[m][n][r]);
            }
        }
}

// ---------------------------------------------------------------------------
// Attention: per-thread q-row, online softmax, K/V staged in LDS chunks of 64.
// qb: (b*2048, 512) bf16. kvb: (b*512, 1024) = [K | V]. ao: (b*2048, 512).
// mask8: normalized uint8 (4,512). grid: (16, heads, b), 128 threads.
// ---------------------------------------------------------------------------
__global__ __launch_bounds__(128) void attn_kernel(const u16* __restrict__ qb,
                                                   const u16* __restrict__ kvb,
                                                   const unsigned char* __restrict__ mask8,
                                                   u16* __restrict__ ao) {
    __shared__ u16 kc[64][72];
    __shared__ u16 vc[64][72];
    const int tid = threadIdx.x;
    const int h = blockIdx.y, bbi = blockIdx.z;
    const int qrow = blockIdx.x * 128 + tid;
    const unsigned char* mrow = mask8 + (size_t)bbi * 512;

    float qf[64];
    const u16* qp = qb + ((size_t)(bbi * 2048 + qrow)) * 512 + h * 64;
#pragma unroll
    for (int c = 0; c < 8; ++c) {
        u16x8 u = *(const u16x8*)(qp + c * 8);
#pragma unroll
        for (int i = 0; i < 8; ++i) qf[c * 8 + i] = b2f(u[i]) * 0.125f;
    }
    float mrun = -3.0e38f, lrun = 0.f;
    float acc[64];
#pragma unroll
    for (int i = 0; i < 64; ++i) acc[i] = 0.f;

    const int sr = tid >> 4;        // 0..7
    const int sh = (tid >> 3) & 1;  // 0: k half, 1: v half
    const int sc = (tid & 7) * 8;   // 0..56
    const u16* kvb_b = kvb + (size_t)bbi * 512 * 1024 + h * 64 + sh * 512 + sc;

    for (int j0 = 0; j0 < 512; j0 += 64) {
        __syncthreads();
#pragma unroll
        for (int p = 0; p < 8; ++p) {
            int r = p * 8 + sr;
            u16x8 u = *(const u16x8*)(kvb_b + (size_t)(j0 + r) * 1024);
            if (sh)
                *(u16x8*)(&vc[r][sc]) = u;
            else
                *(u16x8*)(&kc[r][sc]) = u;
        }
        __syncthreads();
        for (int j = 0; j < 64; ++j) {
            if (!mrow[j0 + j]) continue;  // wave-uniform skip
            float s0 = 0.f, s1 = 0.f, s2 = 0.f, s3 = 0.f;
#pragma unroll
            for (int c = 0; c < 8; ++c) {
                u16x8 u = *(const u16x8*)(&kc[j][c * 8]);
                s0 += qf[c * 8 + 0] * b2f(u[0]);
                s1 += qf[c * 8 + 1] * b2f(u[1]);
                s2 += qf[c * 8 + 2] * b2f(u[2]);
                s3 += qf[c * 8 + 3] * b2f(u[3]);
                s0 += qf[c * 8 + 4] * b2f(u[4]);
                s1 += qf[c * 8 + 5] * b2f(u[5]);
                s2 += qf[c * 8 + 6] * b2f(u[6]);
                s3 += qf[c * 8 + 7] * b2f(u[7]);
            }
            float s = (s0 + s1) + (s2 + s3);
            float mn = fmaxf(mrun, s);
            float p = __expf(s - mn);
            if (mn > mrun) {
                float corr = __expf(mrun - mn);
                lrun *= corr;
#pragma unroll
                for (int i = 0; i < 64; ++i) acc[i] *= corr;
                mrun = mn;
            }
            lrun += p;
#pragma unroll
            for (int c = 0; c < 8; ++c) {
                u16x8 u = *(const u16x8*)(&vc[j][c * 8]);
#pragma unroll
                for (int i = 0; i < 8; ++i) acc[c * 8 + i] += p * b2f(u[i]);
            }
        }
    }
    float inv = (lrun > 0.f) ? (1.f / lrun) : 0.f;
    u16* op = ao + ((size_t)(bbi * 2048 + qrow)) * 512 + h * 64;
#pragma unroll
    for (int c = 0; c < 8; ++c) {
        u16x8 o;
#pragma unroll
        for (int i = 0; i < 8; ++i) o[i] = f2bf(acc[c * 8 + i] * inv);
        *(u16x8*)(op + c * 8) = o;
    }
}

// ---------------------------------------------------------------------------
// Inputs: FLOAT32. Output d_out: FLOAT32 (32 MB) — rounds 3-4 failed by
// writing bf16 here; the final GEMM now stores f32 directly.
// xn (bf16, 16MB) lives in d_out[0..16MB) (final GEMM overwrites all 32MB).
// ws use = 28 MB + 4 KB.
// ---------------------------------------------------------------------------
extern "C" void kernel_launch(void* const* d_in, const int* in_sizes, int n_in,
                              void* d_out, int out_size, void* d_ws, size_t ws_size,
                              hipStream_t stream) {
    const float* x = (const float*)d_in[0];      // (4,2048,1024) f32
    const float* media = (const float*)d_in[1];  // (4,512,1024) f32
    const unsigned char* mask = (const unsigned char*)d_in[2];  // (4,512)
    const float* ln_g = (const float*)d_in[3];   // (1024) f32
    const float* ln_b = (const float*)d_in[4];   // (1024) f32
    const float* Wq = (const float*)d_in[5];     // (1024,512) f32
    const float* Wkv = (const float*)d_in[6];    // (1024,1024) f32
    const float* Wo = (const float*)d_in[7];     // (512,1024) f32
    float* out = (float*)d_out;                  // (4,2048,1024) f32

    char* w = (char*)d_ws;
    unsigned char* mask8 = (unsigned char*)w; w += 4096;
    u16* qb = (u16*)w;     w += (size_t)8192 * 512 * 2;   //  8 MB
    u16* kvb = (u16*)w;    w += (size_t)2048 * 1024 * 2;  //  4 MB
    u16* ao = (u16*)w;     w += (size_t)8192 * 512 * 2;   //  8 MB
    u16* mediab = (u16*)w; w += (size_t)2048 * 1024 * 2;  //  4 MB
    u16* wqb = (u16*)w;    w += (size_t)1024 * 512 * 2;   //  1 MB
    u16* wkvb = (u16*)w;   w += (size_t)1024 * 1024 * 2;  //  2 MB
    u16* wob = (u16*)w;    w += (size_t)512 * 1024 * 2;   //  1 MB
    u16* xn = (u16*)d_out; // first 16MB of d_out; final GEMM overwrites all

    prep_mask<<<1, 256, 0, stream>>>(mask, mask8, 2048);
    cvt_kernel<<<1024, 256, 0, stream>>>(media, mediab, 2048 * 1024 / 8);
    cvt_kernel<<<256, 256, 0, stream>>>(Wq, wqb, 1024 * 512 / 8);
    cvt_kernel<<<512, 256, 0, stream>>>(Wkv, wkvb, 1024 * 1024 / 8);
    cvt_kernel<<<256, 256, 0, stream>>>(Wo, wob, 512 * 1024 / 8);
    ln_kernel<<<2048, 256, 0, stream>>>(x, ln_g, ln_b, xn);
    // q = xn @ Wq   (8192x1024 @ 1024x512), bf16 out
    gemm_nn<0><<<dim3(512 / 128, 8192 / 128), 256, 0, stream>>>(xn, wqb, (void*)qb, 8192, 512, 1024);
    // kv = media @ Wkv  (2048x1024 @ 1024x1024), bf16 out
    gemm_nn<0><<<dim3(1024 / 128, 2048 / 128), 256, 0, stream>>>(mediab, wkvb, (void*)kvb, 2048, 1024, 1024);
    // attention (scale folded into q inside kernel)
    attn_kernel<<<dim3(16, 8, 4), 128, 0, stream>>>(qb, kvb, mask8, ao);
    // out = ao @ Wo  (8192x512 @ 512x1024), F32 out
    gemm_nn<1><<<dim3(1024 / 128, 8192 / 128), 256, 0, stream>>>(ao, wob, (void*)out, 8192, 1024, 512);
}

// Round 7
// 224.927 us; speedup vs baseline: 2.0098x; 2.0098x over previous
//
#include <hip/hip_runtime.h>
#include <hip/hip_bf16.h>

typedef unsigned short u16;
typedef __attribute__((ext_vector_type(4))) unsigned short u16x4;
typedef __attribute__((ext_vector_type(8))) unsigned short u16x8;
typedef __attribute__((ext_vector_type(8))) short bf16x8;
typedef __attribute__((ext_vector_type(4))) float f32x4;

__device__ __forceinline__ float b2f(u16 v) {
    return __uint_as_float(((unsigned)v) << 16);
}
__device__ __forceinline__ u16 f2bf(float f) {
    unsigned u = __float_as_uint(f);
    unsigned r = (u + 0x7fffu + ((u >> 16) & 1u)) >> 16;
    return (u16)r;
}

// ---------------------------------------------------------------------------
// Mask normalize: detect {bool8, int32, float32} encoding, write uint8[2048].
// ---------------------------------------------------------------------------
__global__ void prep_mask(const unsigned char* __restrict__ mb,
                          unsigned char* __restrict__ mout, int n) {
    __shared__ int c0s, c1s;
    if (threadIdx.x == 0) { c0s = 0; c1s = 0; }
    __syncthreads();
    int a0 = 0, a1 = 0;
    for (int i = threadIdx.x; i < 2048; i += 256) {
        if (mb[i]) {
            int cl = i & 3;
            if (cl == 0) a0 = 1;
            else if (cl == 1) a1 = 1;
        }
    }
    if (a0) atomicOr(&c0s, 1);
    if (a1) atomicOr(&c1s, 1);
    __syncthreads();
    int fmt = c1s ? 1 : (c0s ? 0 : 2);  // 1=bool8, 0=int32, 2=float32
    for (int e = threadIdx.x; e < n; e += 256) {
        unsigned char v;
        if (fmt == 1)      v = (mb[e] != 0);
        else if (fmt == 0) v = (((const int*)mb)[e] != 0);
        else               v = (((const float*)mb)[e] != 0.f);
        mout[e] = v;
    }
}

// ---------------------------------------------------------------------------
// f32 -> bf16 convert, 8 elems/thread.
// ---------------------------------------------------------------------------
__global__ __launch_bounds__(256) void cvt_kernel(const float* __restrict__ in,
                                                  u16* __restrict__ out, int n8) {
    int i = blockIdx.x * 256 + threadIdx.x;
    if (i >= n8) return;
    float4 a = ((const float4*)in)[i * 2];
    float4 b = ((const float4*)in)[i * 2 + 1];
    u16x8 o;
    o[0] = f2bf(a.x); o[1] = f2bf(a.y); o[2] = f2bf(a.z); o[3] = f2bf(a.w);
    o[4] = f2bf(b.x); o[5] = f2bf(b.y); o[6] = f2bf(b.z); o[7] = f2bf(b.w);
    ((u16x8*)out)[i] = o;
}

// ---------------------------------------------------------------------------
// LayerNorm: 8192 rows x 1024 f32 in, bf16 out. One wave per row, 4 rows/block.
// ---------------------------------------------------------------------------
__global__ __launch_bounds__(256) void ln_kernel(const float* __restrict__ x,
                                                 const float* __restrict__ g,
                                                 const float* __restrict__ bta,
                                                 u16* __restrict__ y) {
    const int lane = threadIdx.x & 63;
    const int row = blockIdx.x * 4 + (threadIdx.x >> 6);
    const float* xr = x + (size_t)row * 1024;
    float v[16];
    float sum = 0.f, sq = 0.f;
#pragma unroll
    for (int c = 0; c < 4; ++c) {
        float4 u = ((const float4*)xr)[c * 64 + lane];
        v[c * 4 + 0] = u.x; v[c * 4 + 1] = u.y; v[c * 4 + 2] = u.z; v[c * 4 + 3] = u.w;
        sum += u.x + u.y + u.z + u.w;
        sq += u.x * u.x + u.y * u.y + u.z * u.z + u.w * u.w;
    }
#pragma unroll
    for (int o = 1; o < 64; o <<= 1) {
        sum += __shfl_xor(sum, o, 64);
        sq += __shfl_xor(sq, o, 64);
    }
    float mean = sum * (1.f / 1024.f);
    float var = sq * (1.f / 1024.f) - mean * mean;
    float rs = rsqrtf(var + 1e-5f);
    u16* yr = y + (size_t)row * 1024;
#pragma unroll
    for (int c = 0; c < 4; ++c) {
        float4 ug = ((const float4*)g)[c * 64 + lane];
        float4 ub = ((const float4*)bta)[c * 64 + lane];
        u16x4 o;
        o[0] = f2bf((v[c * 4 + 0] - mean) * rs * ug.x + ub.x);
        o[1] = f2bf((v[c * 4 + 1] - mean) * rs * ug.y + ub.y);
        o[2] = f2bf((v[c * 4 + 2] - mean) * rs * ug.z + ub.z);
        o[3] = f2bf((v[c * 4 + 3] - mean) * rs * ug.w + ub.w);
        *(u16x4*)(yr + c * 256 + lane * 4) = o;
    }
}

// ---------------------------------------------------------------------------
// Generic bf16 GEMM: C(MxN) = A(MxK) @ B(KxN), A,B row-major bf16.
// C output: bf16 (OUTF32=0) or f32 (OUTF32=1).
// ---------------------------------------------------------------------------
template <int OUTF32>
__global__ __launch_bounds__(256, 2) void gemm_nn(const u16* __restrict__ A,
                                                  const u16* __restrict__ B,
                                                  void* __restrict__ Cv,
                                                  int M, int N, int K) {
    __shared__ u16 As[128][40];
    __shared__ u16 Bs[128][40];
    const int tid = threadIdx.x;
    const int lane = tid & 63;
    const int w = tid >> 6;
    const int wm = w >> 1, wn = w & 1;
    const int l15 = lane & 15, l4 = lane >> 4;
    const int row0 = blockIdx.y * 128;
    const int col0 = blockIdx.x * 128;

    f32x4 zero = {0.f, 0.f, 0.f, 0.f};
    f32x4 acc[4][4];
#pragma unroll
    for (int i = 0; i < 4; ++i)
#pragma unroll
        for (int j = 0; j < 4; ++j) acc[i][j] = zero;

    const int ar = tid >> 2, ak = (tid & 3) * 8;
    const int bk = tid >> 4, bc = (tid & 15) * 8;

    for (int k0 = 0; k0 < K; k0 += 32) {
        __syncthreads();
#pragma unroll
        for (int p = 0; p < 2; ++p) {
            int r = ar + p * 64;
            u16x8 va = *(const u16x8*)(A + (size_t)(row0 + r) * K + (k0 + ak));
            *(u16x8*)(&As[r][ak]) = va;
        }
#pragma unroll
        for (int p = 0; p < 2; ++p) {
            int kk = bk + p * 16;
            u16x8 vb = *(const u16x8*)(B + (size_t)(k0 + kk) * N + (col0 + bc));
#pragma unroll
            for (int i = 0; i < 8; ++i) Bs[bc + i][kk] = vb[i];
        }
        __syncthreads();
        bf16x8 aF[4], bF[4];
#pragma unroll
        for (int m = 0; m < 4; ++m)
            aF[m] = *(const bf16x8*)(&As[wm * 64 + m * 16 + l15][l4 * 8]);
#pragma unroll
        for (int n = 0; n < 4; ++n)
            bF[n] = *(const bf16x8*)(&Bs[wn * 64 + n * 16 + l15][l4 * 8]);
#pragma unroll
        for (int m = 0; m < 4; ++m)
#pragma unroll
            for (int n = 0; n < 4; ++n)
                acc[m][n] = __builtin_amdgcn_mfma_f32_16x16x32_bf16(aF[m], bF[n], acc[m][n], 0, 0, 0);
    }
#pragma unroll
    for (int m = 0; m < 4; ++m)
#pragma unroll
        for (int n = 0; n < 4; ++n) {
            int row = row0 + wm * 64 + m * 16 + l4 * 4;
            int col = col0 + wn * 64 + n * 16 + l15;
#pragma unroll
            for (int r = 0; r < 4; ++r) {
                if (OUTF32)
                    ((float*)Cv)[(size_t)(row + r) * N + col] = acc[m][n][r];
                else
                    ((u16*)Cv)[(size_t)(row + r) * N + col] = f2bf(acc[m][n][r]);
            }
        }
}

// ---------------------------------------------------------------------------
// MFMA flash attention. Block = 4 waves (256 thr), QBLK=64 (16 q-rows/wave),
// KVBLK=32, head dim 64. Grid (2048/64, 8 heads, 4 batch).
// qb: (b*2048, 512) bf16; kvb: (b*512, 1024) = [K | V]; ao: (b*2048, 512).
//
// Layout facts (transitively verified by the passing gemm_nn):
//   A-frag 16x16x32: lane holds A[row=l&15][k=(l>>4)*8+i]
//   B-frag: lane holds B[k=(l>>4)*8+i][col=l&15]  (== A-pattern on B^T tile)
//   D-frag: lane holds D[row=(l>>4)*4+r][col=l&15]
// ---------------------------------------------------------------------------
__global__ __launch_bounds__(256) void attn_mfma(const u16* __restrict__ qb,
                                                 const u16* __restrict__ kvb,
                                                 const unsigned char* __restrict__ mask8,
                                                 u16* __restrict__ ao) {
    __shared__ u16 Ks[32][72];      // K tile [j][d]
    __shared__ u16 Vt[64][40];      // V^T tile [d][j]
    __shared__ u16 Pl[4][16][40];   // per-wave P transpose [q][j]
    const int tid = threadIdx.x;
    const int l = tid & 63, w = tid >> 6;
    const int l15 = l & 15, l4 = l >> 4;
    const int h = blockIdx.y, bbi = blockIdx.z;
    const int n0 = blockIdx.x * 64;
    const unsigned char* mrow = mask8 + (size_t)bbi * 512;

    // Q fragments for this wave's 16 q-rows (row = l15)
    const u16* qp = qb + ((size_t)(bbi * 2048 + n0 + w * 16 + l15)) * 512 + h * 64;
    const bf16x8 qf0 = *(const bf16x8*)(qp + l4 * 8);        // d 0..31
    const bf16x8 qf1 = *(const bf16x8*)(qp + 32 + l4 * 8);   // d 32..63

    const f32x4 zero = {0.f, 0.f, 0.f, 0.f};
    f32x4 acc[4];  // O accum: acc[dt][r] = O[q=l4*4+r][d=dt*16+l15]
#pragma unroll
    for (int dt = 0; dt < 4; ++dt) acc[dt] = zero;
    float mrun[4] = {-3.0e38f, -3.0e38f, -3.0e38f, -3.0e38f};
    float lrun[4] = {0.f, 0.f, 0.f, 0.f};

    // staging assignments
    const int kj = tid >> 3, kd = (tid & 7) * 8;   // K: coalesced rows
    const int vj = tid & 31, vd = (tid >> 5) * 8;  // V: transpose-friendly
    const u16* kbase = kvb + ((size_t)bbi * 512) * 1024 + h * 64;

    for (int j0 = 0; j0 < 512; j0 += 32) {
        __syncthreads();
        // stage K [32][64]
        u16x8 kv_ = *(const u16x8*)(kbase + (size_t)(j0 + kj) * 1024 + kd);
        *(u16x8*)(&Ks[kj][kd]) = kv_;
        // stage V transposed
        u16x8 vv = *(const u16x8*)(kbase + (size_t)(j0 + vj) * 1024 + 512 + vd);
#pragma unroll
        for (int i = 0; i < 8; ++i) Vt[vd + i][vj] = vv[i];
        __syncthreads();

        // ---- S = Q K^T (16q x 32j), 4 MFMA ----
        f32x4 s[2];
#pragma unroll
        for (int jt = 0; jt < 2; ++jt) {
            bf16x8 kf0 = *(const bf16x8*)(&Ks[jt * 16 + l15][l4 * 8]);
            bf16x8 kf1 = *(const bf16x8*)(&Ks[jt * 16 + l15][32 + l4 * 8]);
            s[jt] = __builtin_amdgcn_mfma_f32_16x16x32_bf16(qf0, kf0, zero, 0, 0, 0);
            s[jt] = __builtin_amdgcn_mfma_f32_16x16x32_bf16(qf1, kf1, s[jt], 0, 0, 0);
        }
        const float mv0 = mrow[j0 + l15] ? 0.f : -3.0e38f;
        const float mv1 = mrow[j0 + 16 + l15] ? 0.f : -3.0e38f;

        // ---- online softmax per q-row r ----
#pragma unroll
        for (int r = 0; r < 4; ++r) {
            float s0 = s[0][r] * 0.125f + mv0;   // masked -> ~-3e38
            float s1 = s[1][r] * 0.125f + mv1;
            float tmax = fmaxf(s0, s1);
#pragma unroll
            for (int o = 1; o < 16; o <<= 1) tmax = fmaxf(tmax, __shfl_xor(tmax, o, 64));
            float mn = fmaxf(mrun[r], tmax);
            float p0 = (s0 > -1.0e37f) ? __expf(s0 - mn) : 0.f;
            float p1 = (s1 > -1.0e37f) ? __expf(s1 - mn) : 0.f;
            float corr = __expf(mrun[r] - mn);   // 1 if max unchanged
            mrun[r] = mn;
            float psum = p0 + p1;
#pragma unroll
            for (int o = 1; o < 16; o <<= 1) psum += __shfl_xor(psum, o, 64);
            lrun[r] = lrun[r] * corr + psum;
#pragma unroll
            for (int dt = 0; dt < 4; ++dt) acc[dt][r] *= corr;  // per-row rescale (r6 bug: scaled all rows)
            // P -> LDS (per-wave, within-wave ordering only)
            Pl[w][l4 * 4 + r][l15] = f2bf(p0);
            Pl[w][l4 * 4 + r][16 + l15] = f2bf(p1);
        }
        // ---- O += P V (4 MFMA) ----
        bf16x8 pf = *(const bf16x8*)(&Pl[w][l15][l4 * 8]);
#pragma unroll
        for (int dt = 0; dt < 4; ++dt) {
            bf16x8 vf = *(const bf16x8*)(&Vt[dt * 16 + l15][l4 * 8]);
            acc[dt] = __builtin_amdgcn_mfma_f32_16x16x32_bf16(pf, vf, acc[dt], 0, 0, 0);
        }
    }

    // epilogue: O / lrun
    float inv[4];
#pragma unroll
    for (int r = 0; r < 4; ++r) inv[r] = (lrun[r] > 0.f) ? (1.f / lrun[r]) : 0.f;
    u16* op = ao + ((size_t)(bbi * 2048 + n0 + w * 16)) * 512 + h * 64;
#pragma unroll
    for (int dt = 0; dt < 4; ++dt)
#pragma unroll
        for (int r = 0; r < 4; ++r)
            op[(size_t)(l4 * 4 + r) * 512 + dt * 16 + l15] = f2bf(acc[dt][r] * inv[r]);
}

// ---------------------------------------------------------------------------
// Inputs: FLOAT32; output d_out: FLOAT32 (32 MB).
// xn (bf16, 16MB) lives in d_out[0..16MB) (final GEMM overwrites all 32MB).
// ws use = 28 MB + 4 KB.
// ---------------------------------------------------------------------------
extern "C" void kernel_launch(void* const* d_in, const int* in_sizes, int n_in,
                              void* d_out, int out_size, void* d_ws, size_t ws_size,
                              hipStream_t stream) {
    const float* x = (const float*)d_in[0];
    const float* media = (const float*)d_in[1];
    const unsigned char* mask = (const unsigned char*)d_in[2];
    const float* ln_g = (const float*)d_in[3];
    const float* ln_b = (const float*)d_in[4];
    const float* Wq = (const float*)d_in[5];
    const float* Wkv = (const float*)d_in[6];
    const float* Wo = (const float*)d_in[7];
    float* out = (float*)d_out;

    char* w = (char*)d_ws;
    unsigned char* mask8 = (unsigned char*)w; w += 4096;
    u16* qb = (u16*)w;     w += (size_t)8192 * 512 * 2;
    u16* kvb = (u16*)w;    w += (size_t)2048 * 1024 * 2;
    u16* ao = (u16*)w;     w += (size_t)8192 * 512 * 2;
    u16* mediab = (u16*)w; w += (size_t)2048 * 1024 * 2;
    u16* wqb = (u16*)w;    w += (size_t)1024 * 512 * 2;
    u16* wkvb = (u16*)w;   w += (size_t)1024 * 1024 * 2;
    u16* wob = (u16*)w;    w += (size_t)512 * 1024 * 2;
    u16* xn = (u16*)d_out;

    prep_mask<<<1, 256, 0, stream>>>(mask, mask8, 2048);
    cvt_kernel<<<1024, 256, 0, stream>>>(media, mediab, 2048 * 1024 / 8);
    cvt_kernel<<<256, 256, 0, stream>>>(Wq, wqb, 1024 * 512 / 8);
    cvt_kernel<<<512, 256, 0, stream>>>(Wkv, wkvb, 1024 * 1024 / 8);
    cvt_kernel<<<256, 256, 0, stream>>>(Wo, wob, 512 * 1024 / 8);
    ln_kernel<<<2048, 256, 0, stream>>>(x, ln_g, ln_b, xn);
    gemm_nn<0><<<dim3(512 / 128, 8192 / 128), 256, 0, stream>>>(xn, wqb, (void*)qb, 8192, 512, 1024);
    gemm_nn<0><<<dim3(1024 / 128, 2048 / 128), 256, 0, stream>>>(mediab, wkvb, (void*)kvb, 2048, 1024, 1024);
    attn_mfma<<<dim3(32, 8, 4), 256, 0, stream>>>(qb, kvb, mask8, ao);
    gemm_nn<1><<<dim3(1024 / 128, 8192 / 128), 256, 0, stream>>>(ao, wob, (void*)out, 8192, 1024, 512);
}

// Round 8
// 125.285 us; speedup vs baseline: 3.6082x; 1.7953x over previous
//
#include <hip/hip_runtime.h>
#include <hip/hip_bf16.h>

typedef unsigned short u16;
typedef __attribute__((ext_vector_type(4))) unsigned short u16x4;
typedef __attribute__((ext_vector_type(8))) unsigned short u16x8;
typedef __attribute__((ext_vector_type(8))) short bf16x8;
typedef __attribute__((ext_vector_type(4))) float f32x4;

__device__ __forceinline__ float b2f(u16 v) {
    return __uint_as_float(((unsigned)v) << 16);
}
__device__ __forceinline__ u16 f2bf(float f) {
    unsigned u = __float_as_uint(f);
    unsigned r = (u + 0x7fffu + ((u >> 16) & 1u)) >> 16;
    return (u16)r;
}

// ---------------------------------------------------------------------------
// Mask normalize + compact. Detect {bool8,int32,float32} encoding, then per
// batch (one wave each) ballot-compact valid key indices into idx[b][.] and
// write cnts[b]. idx padded to a multiple of 32 with index 0 (tail lanes are
// excluded by the j<cnt test in attention, so padding rows are never used).
// ---------------------------------------------------------------------------
__global__ void prep_mask(const unsigned char* __restrict__ mb,
                          unsigned char* __restrict__ mout,
                          int* __restrict__ idx, int* __restrict__ cnts) {
    __shared__ int c0s, c1s;
    const int tid = threadIdx.x;
    if (tid == 0) { c0s = 0; c1s = 0; }
    __syncthreads();
    int a0 = 0, a1 = 0;
    for (int i = tid; i < 2048; i += 256) {
        if (mb[i]) {
            int cl = i & 3;
            if (cl == 0) a0 = 1;
            else if (cl == 1) a1 = 1;
        }
    }
    if (a0) atomicOr(&c0s, 1);
    if (a1) atomicOr(&c1s, 1);
    __syncthreads();
    int fmt = c1s ? 1 : (c0s ? 0 : 2);  // 1=bool8, 0=int32, 2=float32
    for (int e = tid; e < 2048; e += 256) {
        unsigned char v;
        if (fmt == 1)      v = (mb[e] != 0);
        else if (fmt == 0) v = (((const int*)mb)[e] != 0);
        else               v = (((const float*)mb)[e] != 0.f);
        mout[e] = v;
    }
    __syncthreads();
    // compaction: wave wv handles batch wv
    const int wv = tid >> 6, l = tid & 63;
    int off = 0;
#pragma unroll
    for (int c = 0; c < 8; ++c) {
        int key = c * 64 + l;
        bool v = mout[wv * 512 + key] != 0;
        unsigned long long m = __ballot(v);
        int rank = __popcll(m & ((1ull << l) - 1ull));
        if (v) idx[wv * 512 + off + rank] = key;
        off += __popcll(m);
    }
    if (l == 0) cnts[wv] = off;
    int nt = (off + 31) & ~31;
    for (int p = off + l; p < nt; p += 64) idx[wv * 512 + p] = 0;
}

// ---------------------------------------------------------------------------
// f32 -> bf16 convert, 8 elems/thread.
// ---------------------------------------------------------------------------
__global__ __launch_bounds__(256) void cvt_kernel(const float* __restrict__ in,
                                                  u16* __restrict__ out, int n8) {
    int i = blockIdx.x * 256 + threadIdx.x;
    if (i >= n8) return;
    float4 a = ((const float4*)in)[i * 2];
    float4 b = ((const float4*)in)[i * 2 + 1];
    u16x8 o;
    o[0] = f2bf(a.x); o[1] = f2bf(a.y); o[2] = f2bf(a.z); o[3] = f2bf(a.w);
    o[4] = f2bf(b.x); o[5] = f2bf(b.y); o[6] = f2bf(b.z); o[7] = f2bf(b.w);
    ((u16x8*)out)[i] = o;
}

// ---------------------------------------------------------------------------
// Fused transpose-convert of the 3 weight matrices: out(N,K) bf16 from
// in(K,N) f32. 64x64 tile via LDS. blockIdx.z selects the weight.
// ---------------------------------------------------------------------------
__global__ __launch_bounds__(256) void tcvt_w(const float* __restrict__ Wq,
                                              const float* __restrict__ Wkv,
                                              const float* __restrict__ Wo,
                                              u16* __restrict__ wqt,
                                              u16* __restrict__ wkvt,
                                              u16* __restrict__ wot) {
    __shared__ u16 T[64][72];
    const int z = blockIdx.z;
    const float* in; u16* out; int K, N;
    if (z == 0)      { in = Wq;  out = wqt;  K = 1024; N = 512; }
    else if (z == 1) { in = Wkv; out = wkvt; K = 1024; N = 1024; }
    else             { in = Wo;  out = wot;  K = 512;  N = 1024; }
    const int k0 = blockIdx.y * 64, n0 = blockIdx.x * 64;
    if (k0 >= K || n0 >= N) return;
    const int tid = threadIdx.x;
#pragma unroll
    for (int p = 0; p < 4; ++p) {
        int kr = p * 16 + (tid >> 4);
        float4 u = *(const float4*)(in + (size_t)(k0 + kr) * N + n0 + (tid & 15) * 4);
        u16x4 o4;
        o4[0] = f2bf(u.x); o4[1] = f2bf(u.y); o4[2] = f2bf(u.z); o4[3] = f2bf(u.w);
        *(u16x4*)(&T[kr][(tid & 15) * 4]) = o4;
    }
    __syncthreads();
    const int n = tid >> 2, kc = (tid & 3) * 16;
#pragma unroll
    for (int hh = 0; hh < 2; ++hh) {
        u16x8 o;
#pragma unroll
        for (int i = 0; i < 8; ++i) o[i] = T[kc + hh * 8 + i][n];
        *(u16x8*)(out + (size_t)(n0 + n) * K + k0 + kc + hh * 8) = o;
    }
}

// ---------------------------------------------------------------------------
// LayerNorm: 8192 rows x 1024 f32 in, bf16 out. One wave per row, 4 rows/block.
// ---------------------------------------------------------------------------
__global__ __launch_bounds__(256) void ln_kernel(const float* __restrict__ x,
                                                 const float* __restrict__ g,
                                                 const float* __restrict__ bta,
                                                 u16* __restrict__ y) {
    const int lane = threadIdx.x & 63;
    const int row = blockIdx.x * 4 + (threadIdx.x >> 6);
    const float* xr = x + (size_t)row * 1024;
    float v[16];
    float sum = 0.f, sq = 0.f;
#pragma unroll
    for (int c = 0; c < 4; ++c) {
        float4 u = ((const float4*)xr)[c * 64 + lane];
        v[c * 4 + 0] = u.x; v[c * 4 + 1] = u.y; v[c * 4 + 2] = u.z; v[c * 4 + 3] = u.w;
        sum += u.x + u.y + u.z + u.w;
        sq += u.x * u.x + u.y * u.y + u.z * u.z + u.w * u.w;
    }
#pragma unroll
    for (int o = 1; o < 64; o <<= 1) {
        sum += __shfl_xor(sum, o, 64);
        sq += __shfl_xor(sq, o, 64);
    }
    float mean = sum * (1.f / 1024.f);
    float var = sq * (1.f / 1024.f) - mean * mean;
    float rs = rsqrtf(var + 1e-5f);
    u16* yr = y + (size_t)row * 1024;
#pragma unroll
    for (int c = 0; c < 4; ++c) {
        float4 ug = ((const float4*)g)[c * 64 + lane];
        float4 ub = ((const float4*)bta)[c * 64 + lane];
        u16x4 o;
        o[0] = f2bf((v[c * 4 + 0] - mean) * rs * ug.x + ub.x);
        o[1] = f2bf((v[c * 4 + 1] - mean) * rs * ug.y + ub.y);
        o[2] = f2bf((v[c * 4 + 2] - mean) * rs * ug.z + ub.z);
        o[3] = f2bf((v[c * 4 + 3] - mean) * rs * ug.w + ub.w);
        *(u16x4*)(yr + c * 256 + lane * 4) = o;
    }
}

// ---------------------------------------------------------------------------
// bf16 GEMM with transposed B: C(MxN) = A(MxK) @ Bt(NxK)^T. A,Bt row-major.
// Both operands stage identically: coalesced u16x8 load -> padded LDS tile.
// 128x128 tile, BK=32, 4 waves. C out bf16 (OUTF32=0) or f32 (OUTF32=1).
// ---------------------------------------------------------------------------
template <int OUTF32>
__global__ __launch_bounds__(256, 2) void gemm_nt(const u16* __restrict__ A,
                                                  const u16* __restrict__ Bt,
                                                  void* __restrict__ Cv,
                                                  int M, int N, int K) {
    __shared__ u16 As[128][40];
    __shared__ u16 Bs[128][40];
    const int tid = threadIdx.x;
    const int lane = tid & 63;
    const int w = tid >> 6;
    const int wm = w >> 1, wn = w & 1;
    const int l15 = lane & 15, l4 = lane >> 4;
    const int row0 = blockIdx.y * 128;
    const int col0 = blockIdx.x * 128;

    f32x4 zero = {0.f, 0.f, 0.f, 0.f};
    f32x4 acc[4][4];
#pragma unroll
    for (int i = 0; i < 4; ++i)
#pragma unroll
        for (int j = 0; j < 4; ++j) acc[i][j] = zero;

    const int ar = tid >> 2, ak = (tid & 3) * 8;

    for (int k0 = 0; k0 < K; k0 += 32) {
        __syncthreads();
#pragma unroll
        for (int p = 0; p < 2; ++p) {
            int r = ar + p * 64;
            u16x8 va = *(const u16x8*)(A + (size_t)(row0 + r) * K + (k0 + ak));
            *(u16x8*)(&As[r][ak]) = va;
            u16x8 vb = *(const u16x8*)(Bt + (size_t)(col0 + r) * K + (k0 + ak));
            *(u16x8*)(&Bs[r][ak]) = vb;
        }
        __syncthreads();
        bf16x8 aF[4], bF[4];
#pragma unroll
        for (int m = 0; m < 4; ++m)
            aF[m] = *(const bf16x8*)(&As[wm * 64 + m * 16 + l15][l4 * 8]);
#pragma unroll
        for (int n = 0; n < 4; ++n)
            bF[n] = *(const bf16x8*)(&Bs[wn * 64 + n * 16 + l15][l4 * 8]);
#pragma unroll
        for (int m = 0; m < 4; ++m)
#pragma unroll
            for (int n = 0; n < 4; ++n)
                acc[m][n] = __builtin_amdgcn_mfma_f32_16x16x32_bf16(aF[m], bF[n], acc[m][n], 0, 0, 0);
    }
#pragma unroll
    for (int m = 0; m < 4; ++m)
#pragma unroll
        for (int n = 0; n < 4; ++n) {
            int row = row0 + wm * 64 + m * 16 + l4 * 4;
            int col = col0 + wn * 64 + n * 16 + l15;
#pragma unroll
            for (int r = 0; r < 4; ++r) {
                if (OUTF32)
                    ((float*)Cv)[(size_t)(row + r) * N + col] = acc[m][n][r];
                else
                    ((u16*)Cv)[(size_t)(row + r) * N + col] = f2bf(acc[m][n][r]);
            }
        }
}

// ---------------------------------------------------------------------------
// MFMA flash attention over COMPACTED keys. Block = 2 waves, QBLK=32
// (16 q-rows/wave), KVBLK=32. Grid (2048/32, 8 heads, 4 batch).
// K/V rows gathered via idx[b][j]; loop runs ceil(cnt/32) tiles; tail lanes
// masked by j<cnt. Fragment mappings as verified by gemm_nn/gemm_nt.
// ---------------------------------------------------------------------------
__global__ __launch_bounds__(128) void attn_mfma(const u16* __restrict__ qb,
                                                 const u16* __restrict__ kvb,
                                                 const int* __restrict__ idx,
                                                 const int* __restrict__ cnts,
                                                 u16* __restrict__ ao) {
    __shared__ u16 Ks[32][72];      // K tile [j][d]
    __shared__ u16 Vt[64][40];      // V^T tile [d][j]
    __shared__ u16 Pl[2][16][40];   // per-wave P transpose [q][j]
    const int tid = threadIdx.x;
    const int l = tid & 63, w = tid >> 6;
    const int l15 = l & 15, l4 = l >> 4;
    const int h = blockIdx.y, bbi = blockIdx.z;
    const int n0 = blockIdx.x * 32;
    const int cnt = cnts[bbi];
    const int* ib = idx + bbi * 512;

    const u16* qp = qb + ((size_t)(bbi * 2048 + n0 + w * 16 + l15)) * 512 + h * 64;
    const bf16x8 qf0 = *(const bf16x8*)(qp + l4 * 8);
    const bf16x8 qf1 = *(const bf16x8*)(qp + 32 + l4 * 8);

    const f32x4 zero = {0.f, 0.f, 0.f, 0.f};
    f32x4 acc[4];
#pragma unroll
    for (int dt = 0; dt < 4; ++dt) acc[dt] = zero;
    float mrun[4] = {-3.0e38f, -3.0e38f, -3.0e38f, -3.0e38f};
    float lrun[4] = {0.f, 0.f, 0.f, 0.f};

    // staging: K: thread covers rows kj,kj+16 at cols kd..kd+7.
    //          V: thread covers row vj, dims vd..vd+7 and +32.
    const int kj = tid >> 3, kd = (tid & 7) * 8;
    const int vj = tid & 31, vd = (tid >> 5) * 8;
    const u16* kbase = kvb + ((size_t)bbi * 512) * 1024 + h * 64;

    for (int j0 = 0; j0 < cnt; j0 += 32) {
        __syncthreads();
#pragma unroll
        for (int p = 0; p < 2; ++p) {
            int r = kj + p * 16;
            int row = ib[j0 + r];
            u16x8 kv_ = *(const u16x8*)(kbase + (size_t)row * 1024 + kd);
            *(u16x8*)(&Ks[r][kd]) = kv_;
        }
        {
            int row = ib[j0 + vj];
#pragma unroll
            for (int p = 0; p < 2; ++p) {
                int d0 = vd + p * 32;
                u16x8 vv = *(const u16x8*)(kbase + (size_t)row * 1024 + 512 + d0);
#pragma unroll
                for (int i = 0; i < 8; ++i) Vt[d0 + i][vj] = vv[i];
            }
        }
        __syncthreads();

        // ---- S = Q K^T (16q x 32j), 4 MFMA ----
        f32x4 s[2];
#pragma unroll
        for (int jt = 0; jt < 2; ++jt) {
            bf16x8 kf0 = *(const bf16x8*)(&Ks[jt * 16 + l15][l4 * 8]);
            bf16x8 kf1 = *(const bf16x8*)(&Ks[jt * 16 + l15][32 + l4 * 8]);
            s[jt] = __builtin_amdgcn_mfma_f32_16x16x32_bf16(qf0, kf0, zero, 0, 0, 0);
            s[jt] = __builtin_amdgcn_mfma_f32_16x16x32_bf16(qf1, kf1, s[jt], 0, 0, 0);
        }
        const float mv0 = (j0 + l15 < cnt) ? 0.f : -3.0e38f;        // tail only
        const float mv1 = (j0 + 16 + l15 < cnt) ? 0.f : -3.0e38f;

        // ---- online softmax per q-row r ----
#pragma unroll
        for (int r = 0; r < 4; ++r) {
            float s0 = s[0][r] * 0.125f + mv0;
            float s1 = s[1][r] * 0.125f + mv1;
            float tmax = fmaxf(s0, s1);
#pragma unroll
            for (int o = 1; o < 16; o <<= 1) tmax = fmaxf(tmax, __shfl_xor(tmax, o, 64));
            float mn = fmaxf(mrun[r], tmax);
            float p0 = (s0 > -1.0e37f) ? __expf(s0 - mn) : 0.f;
            float p1 = (s1 > -1.0e37f) ? __expf(s1 - mn) : 0.f;
            float corr = __expf(mrun[r] - mn);
            mrun[r] = mn;
            float psum = p0 + p1;
#pragma unroll
            for (int o = 1; o < 16; o <<= 1) psum += __shfl_xor(psum, o, 64);
            lrun[r] = lrun[r] * corr + psum;
#pragma unroll
            for (int dt = 0; dt < 4; ++dt) acc[dt][r] *= corr;
            Pl[w][l4 * 4 + r][l15] = f2bf(p0);
            Pl[w][l4 * 4 + r][16 + l15] = f2bf(p1);
        }
        // ---- O += P V (4 MFMA) ----
        bf16x8 pf = *(const bf16x8*)(&Pl[w][l15][l4 * 8]);
#pragma unroll
        for (int dt = 0; dt < 4; ++dt) {
            bf16x8 vf = *(const bf16x8*)(&Vt[dt * 16 + l15][l4 * 8]);
            acc[dt] = __builtin_amdgcn_mfma_f32_16x16x32_bf16(pf, vf, acc[dt], 0, 0, 0);
        }
    }

    float inv[4];
#pragma unroll
    for (int r = 0; r < 4; ++r) inv[r] = (lrun[r] > 0.f) ? (1.f / lrun[r]) : 0.f;
    u16* op = ao + ((size_t)(bbi * 2048 + n0 + w * 16)) * 512 + h * 64;
#pragma unroll
    for (int dt = 0; dt < 4; ++dt)
#pragma unroll
        for (int r = 0; r < 4; ++r)
            op[(size_t)(l4 * 4 + r) * 512 + dt * 16 + l15] = f2bf(acc[dt][r] * inv[r]);
}

// ---------------------------------------------------------------------------
// Inputs: FLOAT32; output d_out: FLOAT32 (32 MB).
// xn (bf16, 16MB) lives in d_out[0..16MB) (final GEMM overwrites all 32MB).
// ws use ~= 28 MB + 16 KB.
// ---------------------------------------------------------------------------
extern "C" void kernel_launch(void* const* d_in, const int* in_sizes, int n_in,
                              void* d_out, int out_size, void* d_ws, size_t ws_size,
                              hipStream_t stream) {
    const float* x = (const float*)d_in[0];
    const float* media = (const float*)d_in[1];
    const unsigned char* mask = (const unsigned char*)d_in[2];
    const float* ln_g = (const float*)d_in[3];
    const float* ln_b = (const float*)d_in[4];
    const float* Wq = (const float*)d_in[5];
    const float* Wkv = (const float*)d_in[6];
    const float* Wo = (const float*)d_in[7];
    float* out = (float*)d_out;

    char* w = (char*)d_ws;
    unsigned char* mask8 = (unsigned char*)w; w += 4096;
    int* idx = (int*)w;    w += 2048 * 4;
    int* cnts = (int*)w;   w += 256;
    u16* qb = (u16*)w;     w += (size_t)8192 * 512 * 2;
    u16* kvb = (u16*)w;    w += (size_t)2048 * 1024 * 2;
    u16* ao = (u16*)w;     w += (size_t)8192 * 512 * 2;
    u16* mediab = (u16*)w; w += (size_t)2048 * 1024 * 2;
    u16* wqt = (u16*)w;    w += (size_t)512 * 1024 * 2;
    u16* wkvt = (u16*)w;   w += (size_t)1024 * 1024 * 2;
    u16* wot = (u16*)w;    w += (size_t)1024 * 512 * 2;
    u16* xn = (u16*)d_out;

    prep_mask<<<1, 256, 0, stream>>>(mask, mask8, idx, cnts);
    tcvt_w<<<dim3(16, 16, 3), 256, 0, stream>>>(Wq, Wkv, Wo, wqt, wkvt, wot);
    cvt_kernel<<<1024, 256, 0, stream>>>(media, mediab, 2048 * 1024 / 8);
    ln_kernel<<<2048, 256, 0, stream>>>(x, ln_g, ln_b, xn);
    // q = xn @ Wq   (8192x1024 @ 1024x512)
    gemm_nt<0><<<dim3(4, 64), 256, 0, stream>>>(xn, wqt, (void*)qb, 8192, 512, 1024);
    // kv = media @ Wkv  (2048x1024 @ 1024x1024)
    gemm_nt<0><<<dim3(8, 16), 256, 0, stream>>>(mediab, wkvt, (void*)kvb, 2048, 1024, 1024);
    // attention over compacted keys
    attn_mfma<<<dim3(64, 8, 4), 128, 0, stream>>>(qb, kvb, idx, cnts, ao);
    // out = ao @ Wo  (8192x512 @ 512x1024), f32 out
    gemm_nt<1><<<dim3(8, 64), 256, 0, stream>>>(ao, wot, (void*)out, 8192, 1024, 512);
}

// Round 9
// 99.594 us; speedup vs baseline: 4.5389x; 1.2580x over previous
//
#include <hip/hip_runtime.h>
#include <hip/hip_bf16.h>

typedef unsigned short u16;
typedef __attribute__((ext_vector_type(4))) unsigned short u16x4;
typedef __attribute__((ext_vector_type(8))) unsigned short u16x8;
typedef __attribute__((ext_vector_type(8))) short bf16x8;
typedef __attribute__((ext_vector_type(4))) float f32x4;

__device__ __forceinline__ float b2f(u16 v) {
    return __uint_as_float(((unsigned)v) << 16);
}
__device__ __forceinline__ u16 f2bf(float f) {
    unsigned u = __float_as_uint(f);
    unsigned r = (u + 0x7fffu + ((u >> 16) & 1u)) >> 16;
    return (u16)r;
}

// ---------------------------------------------------------------------------
// prep_all: one launch for all independent preprocessing.
//   blocks [0,2048)    : LayerNorm x -> xn (bf16), 4 rows/block
//   blocks [2048,3072) : media f32 -> bf16
//   blocks [3072,3840) : weight transpose-convert (Wq,Wkv,Wo) -> (N,K) bf16
//   block  3840        : mask detect {bool8,int32,f32} + ballot-compact idx
// Branches are blockIdx-uniform (no divergence).
// ---------------------------------------------------------------------------
__global__ __launch_bounds__(256) void prep_all(
    const float* __restrict__ x, const float* __restrict__ media,
    const unsigned char* __restrict__ mask,
    const float* __restrict__ ln_g, const float* __restrict__ ln_b,
    const float* __restrict__ Wq, const float* __restrict__ Wkv,
    const float* __restrict__ Wo,
    u16* __restrict__ xn, u16* __restrict__ mediab,
    unsigned char* __restrict__ mask8, int* __restrict__ idx,
    int* __restrict__ cnts,
    u16* __restrict__ wqt, u16* __restrict__ wkvt, u16* __restrict__ wot) {
    __shared__ u16 T[64][72];
    __shared__ int c0s, c1s;
    const int bid = blockIdx.x, tid = threadIdx.x;

    if (bid < 2048) {  // ---- LayerNorm ----
        const int lane = tid & 63;
        const int row = bid * 4 + (tid >> 6);
        const float* xr = x + (size_t)row * 1024;
        float v[16];
        float sum = 0.f, sq = 0.f;
#pragma unroll
        for (int c = 0; c < 4; ++c) {
            float4 u = ((const float4*)xr)[c * 64 + lane];
            v[c * 4 + 0] = u.x; v[c * 4 + 1] = u.y; v[c * 4 + 2] = u.z; v[c * 4 + 3] = u.w;
            sum += u.x + u.y + u.z + u.w;
            sq += u.x * u.x + u.y * u.y + u.z * u.z + u.w * u.w;
        }
#pragma unroll
        for (int o = 1; o < 64; o <<= 1) {
            sum += __shfl_xor(sum, o, 64);
            sq += __shfl_xor(sq, o, 64);
        }
        float mean = sum * (1.f / 1024.f);
        float var = sq * (1.f / 1024.f) - mean * mean;
        float rs = rsqrtf(var + 1e-5f);
        u16* yr = xn + (size_t)row * 1024;
#pragma unroll
        for (int c = 0; c < 4; ++c) {
            float4 ug = ((const float4*)ln_g)[c * 64 + lane];
            float4 ub = ((const float4*)ln_b)[c * 64 + lane];
            u16x4 o;
            o[0] = f2bf((v[c * 4 + 0] - mean) * rs * ug.x + ub.x);
            o[1] = f2bf((v[c * 4 + 1] - mean) * rs * ug.y + ub.y);
            o[2] = f2bf((v[c * 4 + 2] - mean) * rs * ug.z + ub.z);
            o[3] = f2bf((v[c * 4 + 3] - mean) * rs * ug.w + ub.w);
            *(u16x4*)(yr + c * 256 + lane * 4) = o;
        }
    } else if (bid < 3072) {  // ---- media f32->bf16 ----
        int i = (bid - 2048) * 256 + tid;  // < 262144
        float4 a = ((const float4*)media)[i * 2];
        float4 b = ((const float4*)media)[i * 2 + 1];
        u16x8 o;
        o[0] = f2bf(a.x); o[1] = f2bf(a.y); o[2] = f2bf(a.z); o[3] = f2bf(a.w);
        o[4] = f2bf(b.x); o[5] = f2bf(b.y); o[6] = f2bf(b.z); o[7] = f2bf(b.w);
        ((u16x8*)mediab)[i] = o;
    } else if (bid < 3840) {  // ---- weight transpose-convert ----
        const int t = bid - 3072;
        const int z = t >> 8, rem = t & 255;
        const float* in; u16* out; int K, N;
        if (z == 0)      { in = Wq;  out = wqt;  K = 1024; N = 512; }
        else if (z == 1) { in = Wkv; out = wkvt; K = 1024; N = 1024; }
        else             { in = Wo;  out = wot;  K = 512;  N = 1024; }
        const int k0 = (rem >> 4) * 64, n0 = (rem & 15) * 64;
        if (k0 >= K || n0 >= N) return;
#pragma unroll
        for (int p = 0; p < 4; ++p) {
            int kr = p * 16 + (tid >> 4);
            float4 u = *(const float4*)(in + (size_t)(k0 + kr) * N + n0 + (tid & 15) * 4);
            u16x4 o4;
            o4[0] = f2bf(u.x); o4[1] = f2bf(u.y); o4[2] = f2bf(u.z); o4[3] = f2bf(u.w);
            *(u16x4*)(&T[kr][(tid & 15) * 4]) = o4;
        }
        __syncthreads();
        const int n = tid >> 2, kc = (tid & 3) * 16;
#pragma unroll
        for (int hh = 0; hh < 2; ++hh) {
            u16x8 o;
#pragma unroll
            for (int i = 0; i < 8; ++i) o[i] = T[kc + hh * 8 + i][n];
            *(u16x8*)(out + (size_t)(n0 + n) * K + k0 + kc + hh * 8) = o;
        }
    } else {  // ---- mask detect + compact ----
        if (tid == 0) { c0s = 0; c1s = 0; }
        __syncthreads();
        int a0 = 0, a1 = 0;
        for (int i = tid; i < 2048; i += 256) {
            if (mask[i]) {
                int cl = i & 3;
                if (cl == 0) a0 = 1;
                else if (cl == 1) a1 = 1;
            }
        }
        if (a0) atomicOr(&c0s, 1);
        if (a1) atomicOr(&c1s, 1);
        __syncthreads();
        int fmt = c1s ? 1 : (c0s ? 0 : 2);  // 1=bool8, 0=int32, 2=float32
        for (int e = tid; e < 2048; e += 256) {
            unsigned char v;
            if (fmt == 1)      v = (mask[e] != 0);
            else if (fmt == 0) v = (((const int*)mask)[e] != 0);
            else               v = (((const float*)mask)[e] != 0.f);
            mask8[e] = v;
        }
        __syncthreads();
        const int wv = tid >> 6, l = tid & 63;
        int off = 0;
#pragma unroll
        for (int c = 0; c < 8; ++c) {
            int key = c * 64 + l;
            bool v = mask8[wv * 512 + key] != 0;
            unsigned long long m = __ballot(v);
            int rank = __popcll(m & ((1ull << l) - 1ull));
            if (v) idx[wv * 512 + off + rank] = key;
            off += __popcll(m);
        }
        if (l == 0) cnts[wv] = off;
        int nt = (off + 31) & ~31;
        for (int p = off + l; p < nt; p += 64) idx[wv * 512 + p] = 0;
    }
}

// ---------------------------------------------------------------------------
// Shared GEMM tile body: C(tile) = A(MxK) @ Bt(NxK)^T, 128x128 tile, BK=32.
// scale applied in epilogue. OUTF32 selects f32 vs bf16 C store.
// ---------------------------------------------------------------------------
template <int OUTF32>
__device__ __forceinline__ void gemm_tile(u16 (*As)[40], u16 (*Bs)[40],
                                          const u16* __restrict__ A,
                                          const u16* __restrict__ Bt,
                                          void* __restrict__ Cv,
                                          int N, int K, int row0, int col0,
                                          float scale) {
    const int tid = threadIdx.x;
    const int lane = tid & 63;
    const int w = tid >> 6;
    const int wm = w >> 1, wn = w & 1;
    const int l15 = lane & 15, l4 = lane >> 4;

    f32x4 zero = {0.f, 0.f, 0.f, 0.f};
    f32x4 acc[4][4];
#pragma unroll
    for (int i = 0; i < 4; ++i)
#pragma unroll
        for (int j = 0; j < 4; ++j) acc[i][j] = zero;

    const int ar = tid >> 2, ak = (tid & 3) * 8;

    for (int k0 = 0; k0 < K; k0 += 32) {
        __syncthreads();
#pragma unroll
        for (int p = 0; p < 2; ++p) {
            int r = ar + p * 64;
            u16x8 va = *(const u16x8*)(A + (size_t)(row0 + r) * K + (k0 + ak));
            *(u16x8*)(&As[r][ak]) = va;
            u16x8 vb = *(const u16x8*)(Bt + (size_t)(col0 + r) * K + (k0 + ak));
            *(u16x8*)(&Bs[r][ak]) = vb;
        }
        __syncthreads();
        bf16x8 aF[4], bF[4];
#pragma unroll
        for (int m = 0; m < 4; ++m)
            aF[m] = *(const bf16x8*)(&As[wm * 64 + m * 16 + l15][l4 * 8]);
#pragma unroll
        for (int n = 0; n < 4; ++n)
            bF[n] = *(const bf16x8*)(&Bs[wn * 64 + n * 16 + l15][l4 * 8]);
#pragma unroll
        for (int m = 0; m < 4; ++m)
#pragma unroll
            for (int n = 0; n < 4; ++n)
                acc[m][n] = __builtin_amdgcn_mfma_f32_16x16x32_bf16(aF[m], bF[n], acc[m][n], 0, 0, 0);
    }
#pragma unroll
    for (int m = 0; m < 4; ++m)
#pragma unroll
        for (int n = 0; n < 4; ++n) {
            int row = row0 + wm * 64 + m * 16 + l4 * 4;
            int col = col0 + wn * 64 + n * 16 + l15;
#pragma unroll
            for (int r = 0; r < 4; ++r) {
                float vv = acc[m][n][r] * scale;
                if (OUTF32)
                    ((float*)Cv)[(size_t)(row + r) * N + col] = vv;
                else
                    ((u16*)Cv)[(size_t)(row + r) * N + col] = f2bf(vv);
            }
        }
}

// ---------------------------------------------------------------------------
// Merged Q + KV projection GEMM (fills the GPU with 384 blocks).
//   blocks [0,256)   : qb = (xn @ Wq) * 0.125   (8192x512, K=1024)
//   blocks [256,384) : kvb = media @ Wkv        (2048x1024, K=1024)
// ---------------------------------------------------------------------------
__global__ __launch_bounds__(256, 2) void qkv_gemm(const u16* __restrict__ xn,
                                                   const u16* __restrict__ wqt,
                                                   u16* __restrict__ qb,
                                                   const u16* __restrict__ mediab,
                                                   const u16* __restrict__ wkvt,
                                                   u16* __restrict__ kvb) {
    __shared__ u16 As[128][40];
    __shared__ u16 Bs[128][40];
    const int b = blockIdx.x;
    const u16 *A, *Bt; u16* C; int N, row0, col0; float sc;
    if (b < 256) { A = xn;     Bt = wqt;  C = qb;  N = 512;  row0 = (b >> 2) * 128; col0 = (b & 3) * 128; sc = 0.125f; }
    else { int t = b - 256; A = mediab; Bt = wkvt; C = kvb; N = 1024; row0 = (t >> 3) * 128; col0 = (t & 7) * 128; sc = 1.f; }
    gemm_tile<0>(As, Bs, A, Bt, (void*)C, N, 1024, row0, col0, sc);
}

// ---------------------------------------------------------------------------
// Output projection: out = ao @ Wo  (8192x1024, K=512), f32 store.
// ---------------------------------------------------------------------------
__global__ __launch_bounds__(256, 2) void o_gemm(const u16* __restrict__ ao,
                                                 const u16* __restrict__ wot,
                                                 float* __restrict__ out) {
    __shared__ u16 As[128][40];
    __shared__ u16 Bs[128][40];
    gemm_tile<1>(As, Bs, ao, wot, (void*)out, 1024, 512,
                 (int)blockIdx.y * 128, (int)blockIdx.x * 128, 1.f);
}

// ---------------------------------------------------------------------------
// MFMA flash attention over COMPACTED keys. Block = 2 waves, QBLK=32
// (16 q-rows/wave), KVBLK=32. Grid (64, 8 heads, 4 batch).
// Q is pre-scaled by 0.125 (folded into qkv_gemm). Index list in LDS.
// ---------------------------------------------------------------------------
__global__ __launch_bounds__(128) void attn_mfma(const u16* __restrict__ qb,
                                                 const u16* __restrict__ kvb,
                                                 const int* __restrict__ idx,
                                                 const int* __restrict__ cnts,
                                                 u16* __restrict__ ao) {
    __shared__ u16 Ks[32][72];      // K tile [j][d]
    __shared__ u16 Vt[64][40];      // V^T tile [d][j]
    __shared__ u16 Pl[2][16][40];   // per-wave P transpose [q][j]
    __shared__ int Is[512];         // compacted key indices
    const int tid = threadIdx.x;
    const int l = tid & 63, w = tid >> 6;
    const int l15 = l & 15, l4 = l >> 4;
    const int h = blockIdx.y, bbi = blockIdx.z;
    const int n0 = blockIdx.x * 32;
    const int cnt = cnts[bbi];
    const int ntile = (cnt + 31) & ~31;
    const int* ib = idx + bbi * 512;
    for (int i = tid; i < ntile; i += 128) Is[i] = ib[i];

    const u16* qp = qb + ((size_t)(bbi * 2048 + n0 + w * 16 + l15)) * 512 + h * 64;
    const bf16x8 qf0 = *(const bf16x8*)(qp + l4 * 8);
    const bf16x8 qf1 = *(const bf16x8*)(qp + 32 + l4 * 8);

    const f32x4 zero = {0.f, 0.f, 0.f, 0.f};
    f32x4 acc[4];
#pragma unroll
    for (int dt = 0; dt < 4; ++dt) acc[dt] = zero;
    float mrun[4] = {-3.0e38f, -3.0e38f, -3.0e38f, -3.0e38f};
    float lrun[4] = {0.f, 0.f, 0.f, 0.f};

    const int kj = tid >> 3, kd = (tid & 7) * 8;
    const int vj = tid & 31, vd = (tid >> 5) * 8;
    const u16* kbase = kvb + ((size_t)bbi * 512) * 1024 + h * 64;

    for (int j0 = 0; j0 < cnt; j0 += 32) {
        __syncthreads();  // first iteration also covers Is writes
#pragma unroll
        for (int p = 0; p < 2; ++p) {
            int r = kj + p * 16;
            int row = Is[j0 + r];
            u16x8 kv_ = *(const u16x8*)(kbase + (size_t)row * 1024 + kd);
            *(u16x8*)(&Ks[r][kd]) = kv_;
        }
        {
            int row = Is[j0 + vj];
#pragma unroll
            for (int p = 0; p < 2; ++p) {
                int d0 = vd + p * 32;
                u16x8 vv = *(const u16x8*)(kbase + (size_t)row * 1024 + 512 + d0);
#pragma unroll
                for (int i = 0; i < 8; ++i) Vt[d0 + i][vj] = vv[i];
            }
        }
        __syncthreads();

        // ---- S = Q K^T (16q x 32j), 4 MFMA ----
        f32x4 s[2];
#pragma unroll
        for (int jt = 0; jt < 2; ++jt) {
            bf16x8 kf0 = *(const bf16x8*)(&Ks[jt * 16 + l15][l4 * 8]);
            bf16x8 kf1 = *(const bf16x8*)(&Ks[jt * 16 + l15][32 + l4 * 8]);
            s[jt] = __builtin_amdgcn_mfma_f32_16x16x32_bf16(qf0, kf0, zero, 0, 0, 0);
            s[jt] = __builtin_amdgcn_mfma_f32_16x16x32_bf16(qf1, kf1, s[jt], 0, 0, 0);
        }
        const float mv0 = (j0 + l15 < cnt) ? 0.f : -3.0e38f;        // tail only
        const float mv1 = (j0 + 16 + l15 < cnt) ? 0.f : -3.0e38f;

        // ---- online softmax per q-row r ----
#pragma unroll
        for (int r = 0; r < 4; ++r) {
            float s0 = s[0][r] + mv0;
            float s1 = s[1][r] + mv1;
            float tmax = fmaxf(s0, s1);
#pragma unroll
            for (int o = 1; o < 16; o <<= 1) tmax = fmaxf(tmax, __shfl_xor(tmax, o, 64));
            float mn = fmaxf(mrun[r], tmax);
            float p0 = (s0 > -1.0e37f) ? __expf(s0 - mn) : 0.f;
            float p1 = (s1 > -1.0e37f) ? __expf(s1 - mn) : 0.f;
            float corr = __expf(mrun[r] - mn);
            mrun[r] = mn;
            float psum = p0 + p1;
#pragma unroll
            for (int o = 1; o < 16; o <<= 1) psum += __shfl_xor(psum, o, 64);
            lrun[r] = lrun[r] * corr + psum;
#pragma unroll
            for (int dt = 0; dt < 4; ++dt) acc[dt][r] *= corr;
            Pl[w][l4 * 4 + r][l15] = f2bf(p0);
            Pl[w][l4 * 4 + r][16 + l15] = f2bf(p1);
        }
        // ---- O += P V (4 MFMA) ----
        bf16x8 pf = *(const bf16x8*)(&Pl[w][l15][l4 * 8]);
#pragma unroll
        for (int dt = 0; dt < 4; ++dt) {
            bf16x8 vf = *(const bf16x8*)(&Vt[dt * 16 + l15][l4 * 8]);
            acc[dt] = __builtin_amdgcn_mfma_f32_16x16x32_bf16(pf, vf, acc[dt], 0, 0, 0);
        }
    }

    float inv[4];
#pragma unroll
    for (int r = 0; r < 4; ++r) inv[r] = (lrun[r] > 0.f) ? (1.f / lrun[r]) : 0.f;
    u16* op = ao + ((size_t)(bbi * 2048 + n0 + w * 16)) * 512 + h * 64;
#pragma unroll
    for (int dt = 0; dt < 4; ++dt)
#pragma unroll
        for (int r = 0; r < 4; ++r)
            op[(size_t)(l4 * 4 + r) * 512 + dt * 16 + l15] = f2bf(acc[dt][r] * inv[r]);
}

// ---------------------------------------------------------------------------
// Inputs: FLOAT32; output d_out: FLOAT32 (32 MB). 4 launches total.
// xn (bf16, 16MB) lives in d_out[0..16MB) (o_gemm overwrites all 32MB).
// ws use ~= 28 MB + 16 KB.
// ---------------------------------------------------------------------------
extern "C" void kernel_launch(void* const* d_in, const int* in_sizes, int n_in,
                              void* d_out, int out_size, void* d_ws, size_t ws_size,
                              hipStream_t stream) {
    const float* x = (const float*)d_in[0];
    const float* media = (const float*)d_in[1];
    const unsigned char* mask = (const unsigned char*)d_in[2];
    const float* ln_g = (const float*)d_in[3];
    const float* ln_b = (const float*)d_in[4];
    const float* Wq = (const float*)d_in[5];
    const float* Wkv = (const float*)d_in[6];
    const float* Wo = (const float*)d_in[7];
    float* out = (float*)d_out;

    char* w = (char*)d_ws;
    unsigned char* mask8 = (unsigned char*)w; w += 4096;
    int* idx = (int*)w;    w += 2048 * 4;
    int* cnts = (int*)w;   w += 256;
    u16* qb = (u16*)w;     w += (size_t)8192 * 512 * 2;
    u16* kvb = (u16*)w;    w += (size_t)2048 * 1024 * 2;
    u16* ao = (u16*)w;     w += (size_t)8192 * 512 * 2;
    u16* mediab = (u16*)w; w += (size_t)2048 * 1024 * 2;
    u16* wqt = (u16*)w;    w += (size_t)512 * 1024 * 2;
    u16* wkvt = (u16*)w;   w += (size_t)1024 * 1024 * 2;
    u16* wot = (u16*)w;    w += (size_t)1024 * 512 * 2;
    u16* xn = (u16*)d_out;

    prep_all<<<3841, 256, 0, stream>>>(x, media, mask, ln_g, ln_b, Wq, Wkv, Wo,
                                       xn, mediab, mask8, idx, cnts, wqt, wkvt, wot);
    qkv_gemm<<<384, 256, 0, stream>>>(xn, wqt, qb, mediab, wkvt, kvb);
    attn_mfma<<<dim3(64, 8, 4), 128, 0, stream>>>(qb, kvb, idx, cnts, ao);
    o_gemm<<<dim3(8, 64), 256, 0, stream>>>(ao, wot, out);
}

// Round 10
// 88.870 us; speedup vs baseline: 5.0866x; 1.1207x over previous
//
#include <hip/hip_runtime.h>
#include <hip/hip_bf16.h>

typedef unsigned short u16;
typedef __attribute__((ext_vector_type(4))) unsigned short u16x4;
typedef __attribute__((ext_vector_type(8))) unsigned short u16x8;
typedef __attribute__((ext_vector_type(8))) short bf16x8;
typedef __attribute__((ext_vector_type(4))) float f32x4;

#define AS1 __attribute__((address_space(1)))
#define AS3 __attribute__((address_space(3)))

__device__ __forceinline__ float b2f(u16 v) {
    return __uint_as_float(((unsigned)v) << 16);
}
__device__ __forceinline__ u16 f2bf(float f) {
    unsigned u = __float_as_uint(f);
    unsigned r = (u + 0x7fffu + ((u >> 16) & 1u)) >> 16;
    return (u16)r;
}

// ---------------------------------------------------------------------------
// prep_all: one launch for all independent preprocessing.
//   blocks [0,2048)    : LayerNorm x -> xn (bf16), 4 rows/block
//   blocks [2048,3072) : media f32 -> bf16
//   blocks [3072,3840) : weight transpose-convert (Wq,Wkv,Wo) -> (N,K) bf16
//   block  3840        : mask detect {bool8,int32,f32} + ballot-compact idx
// ---------------------------------------------------------------------------
__global__ __launch_bounds__(256) void prep_all(
    const float* __restrict__ x, const float* __restrict__ media,
    const unsigned char* __restrict__ mask,
    const float* __restrict__ ln_g, const float* __restrict__ ln_b,
    const float* __restrict__ Wq, const float* __restrict__ Wkv,
    const float* __restrict__ Wo,
    u16* __restrict__ xn, u16* __restrict__ mediab,
    unsigned char* __restrict__ mask8, int* __restrict__ idx,
    int* __restrict__ cnts,
    u16* __restrict__ wqt, u16* __restrict__ wkvt, u16* __restrict__ wot) {
    __shared__ u16 T[64][72];
    __shared__ int c0s, c1s;
    const int bid = blockIdx.x, tid = threadIdx.x;

    if (bid < 2048) {  // ---- LayerNorm ----
        const int lane = tid & 63;
        const int row = bid * 4 + (tid >> 6);
        const float* xr = x + (size_t)row * 1024;
        float v[16];
        float sum = 0.f, sq = 0.f;
#pragma unroll
        for (int c = 0; c < 4; ++c) {
            float4 u = ((const float4*)xr)[c * 64 + lane];
            v[c * 4 + 0] = u.x; v[c * 4 + 1] = u.y; v[c * 4 + 2] = u.z; v[c * 4 + 3] = u.w;
            sum += u.x + u.y + u.z + u.w;
            sq += u.x * u.x + u.y * u.y + u.z * u.z + u.w * u.w;
        }
#pragma unroll
        for (int o = 1; o < 64; o <<= 1) {
            sum += __shfl_xor(sum, o, 64);
            sq += __shfl_xor(sq, o, 64);
        }
        float mean = sum * (1.f / 1024.f);
        float var = sq * (1.f / 1024.f) - mean * mean;
        float rs = rsqrtf(var + 1e-5f);
        u16* yr = xn + (size_t)row * 1024;
#pragma unroll
        for (int c = 0; c < 4; ++c) {
            float4 ug = ((const float4*)ln_g)[c * 64 + lane];
            float4 ub = ((const float4*)ln_b)[c * 64 + lane];
            u16x4 o;
            o[0] = f2bf((v[c * 4 + 0] - mean) * rs * ug.x + ub.x);
            o[1] = f2bf((v[c * 4 + 1] - mean) * rs * ug.y + ub.y);
            o[2] = f2bf((v[c * 4 + 2] - mean) * rs * ug.z + ub.z);
            o[3] = f2bf((v[c * 4 + 3] - mean) * rs * ug.w + ub.w);
            *(u16x4*)(yr + c * 256 + lane * 4) = o;
        }
    } else if (bid < 3072) {  // ---- media f32->bf16 ----
        int i = (bid - 2048) * 256 + tid;
        float4 a = ((const float4*)media)[i * 2];
        float4 b = ((const float4*)media)[i * 2 + 1];
        u16x8 o;
        o[0] = f2bf(a.x); o[1] = f2bf(a.y); o[2] = f2bf(a.z); o[3] = f2bf(a.w);
        o[4] = f2bf(b.x); o[5] = f2bf(b.y); o[6] = f2bf(b.z); o[7] = f2bf(b.w);
        ((u16x8*)mediab)[i] = o;
    } else if (bid < 3840) {  // ---- weight transpose-convert ----
        const int t = bid - 3072;
        const int z = t >> 8, rem = t & 255;
        const float* in; u16* out; int K, N;
        if (z == 0)      { in = Wq;  out = wqt;  K = 1024; N = 512; }
        else if (z == 1) { in = Wkv; out = wkvt; K = 1024; N = 1024; }
        else             { in = Wo;  out = wot;  K = 512;  N = 1024; }
        const int k0 = (rem >> 4) * 64, n0 = (rem & 15) * 64;
        if (k0 >= K || n0 >= N) return;
#pragma unroll
        for (int p = 0; p < 4; ++p) {
            int kr = p * 16 + (tid >> 4);
            float4 u = *(const float4*)(in + (size_t)(k0 + kr) * N + n0 + (tid & 15) * 4);
            u16x4 o4;
            o4[0] = f2bf(u.x); o4[1] = f2bf(u.y); o4[2] = f2bf(u.z); o4[3] = f2bf(u.w);
            *(u16x4*)(&T[kr][(tid & 15) * 4]) = o4;
        }
        __syncthreads();
        const int n = tid >> 2, kc = (tid & 3) * 16;
#pragma unroll
        for (int hh = 0; hh < 2; ++hh) {
            u16x8 o;
#pragma unroll
            for (int i = 0; i < 8; ++i) o[i] = T[kc + hh * 8 + i][n];
            *(u16x8*)(out + (size_t)(n0 + n) * K + k0 + kc + hh * 8) = o;
        }
    } else {  // ---- mask detect + compact ----
        if (tid == 0) { c0s = 0; c1s = 0; }
        __syncthreads();
        int a0 = 0, a1 = 0;
        for (int i = tid; i < 2048; i += 256) {
            if (mask[i]) {
                int cl = i & 3;
                if (cl == 0) a0 = 1;
                else if (cl == 1) a1 = 1;
            }
        }
        if (a0) atomicOr(&c0s, 1);
        if (a1) atomicOr(&c1s, 1);
        __syncthreads();
        int fmt = c1s ? 1 : (c0s ? 0 : 2);  // 1=bool8, 0=int32, 2=float32
        for (int e = tid; e < 2048; e += 256) {
            unsigned char v;
            if (fmt == 1)      v = (mask[e] != 0);
            else if (fmt == 0) v = (((const int*)mask)[e] != 0);
            else               v = (((const float*)mask)[e] != 0.f);
            mask8[e] = v;
        }
        __syncthreads();
        const int wv = tid >> 6, l = tid & 63;
        int off = 0;
#pragma unroll
        for (int c = 0; c < 8; ++c) {
            int key = c * 64 + l;
            bool v = mask8[wv * 512 + key] != 0;
            unsigned long long m = __ballot(v);
            int rank = __popcll(m & ((1ull << l) - 1ull));
            if (v) idx[wv * 512 + off + rank] = key;
            off += __popcll(m);
        }
        if (l == 0) cnts[wv] = off;
        int nt = (off + 31) & ~31;
        for (int p = off + l; p < nt; p += 64) idx[wv * 512 + p] = 0;
    }
}

// ---------------------------------------------------------------------------
// GEMM tile body with global_load_lds staging + XOR-swizzled LDS.
// C(128x128 tile) = A(MxK) @ Bt(NxK)^T, BK=64, 4 waves.
// LDS: linear [128][64] u16 per operand. gload_lds writes lane*16B linearly;
// the SOURCE 16B-slot is pre-swizzled ((l&7)^(l>>3)) so that a read of
// logical slot s at row r uses physical slot s^(r&7)  (rule #21: linear dest
// + inverse-swz source + swz read). Balanced 8 accesses/bank on ds_read_b128.
// ---------------------------------------------------------------------------
template <int OUTF32>
__device__ __forceinline__ void gemm_tile_g(u16* As, u16* Bs,
                                            const u16* __restrict__ A,
                                            const u16* __restrict__ Bt,
                                            void* __restrict__ Cv,
                                            int N, int K, int row0, int col0,
                                            float scale) {
    const int tid = threadIdx.x;
    const int l = tid & 63, w = tid >> 6;
    const int l15 = l & 15, l4 = l >> 4;
    const int wm = w >> 1, wn = w & 1;
    const int lr = l >> 3;                 // row-within-8 for staging
    const int cs = ((l & 7) ^ lr) * 8;     // pre-swizzled source slot (elems)

    f32x4 zero = {0.f, 0.f, 0.f, 0.f};
    f32x4 acc[4][4];
#pragma unroll
    for (int i = 0; i < 4; ++i)
#pragma unroll
        for (int j = 0; j < 4; ++j) acc[i][j] = zero;

    const int rsw = l15 & 7;               // row&7 for all fragment rows

    for (int k0 = 0; k0 < K; k0 += 64) {
        __syncthreads();
#pragma unroll
        for (int i = 0; i < 4; ++i) {
            int r = w * 32 + i * 8;        // wave-uniform 8-row group
            __builtin_amdgcn_global_load_lds(
                (const AS1 void*)(A + (size_t)(row0 + r + lr) * K + k0 + cs),
                (AS3 void*)(As + r * 64), 16, 0, 0);
            __builtin_amdgcn_global_load_lds(
                (const AS1 void*)(Bt + (size_t)(col0 + r + lr) * K + k0 + cs),
                (AS3 void*)(Bs + r * 64), 16, 0, 0);
        }
        __syncthreads();
#pragma unroll
        for (int h = 0; h < 2; ++h) {      // two K=32 sub-steps
            bf16x8 aF[4], bF[4];
#pragma unroll
            for (int m = 0; m < 4; ++m) {
                int s = (h * 4 + l4) ^ rsw;             // swizzled slot
                aF[m] = *(const bf16x8*)(As + (wm * 64 + m * 16 + l15) * 64 + s * 8);
                bF[m] = *(const bf16x8*)(Bs + (wn * 64 + m * 16 + l15) * 64 + s * 8);
            }
#pragma unroll
            for (int m = 0; m < 4; ++m)
#pragma unroll
                for (int n = 0; n < 4; ++n)
                    acc[m][n] = __builtin_amdgcn_mfma_f32_16x16x32_bf16(aF[m], bF[n], acc[m][n], 0, 0, 0);
        }
    }
#pragma unroll
    for (int m = 0; m < 4; ++m)
#pragma unroll
        for (int n = 0; n < 4; ++n) {
            int row = row0 + wm * 64 + m * 16 + l4 * 4;
            int col = col0 + wn * 64 + n * 16 + l15;
#pragma unroll
            for (int r = 0; r < 4; ++r) {
                float vv = acc[m][n][r] * scale;
                if (OUTF32)
                    ((float*)Cv)[(size_t)(row + r) * N + col] = vv;
                else
                    ((u16*)Cv)[(size_t)(row + r) * N + col] = f2bf(vv);
            }
        }
}

// ---------------------------------------------------------------------------
// Merged Q + KV projection GEMM (384 blocks fills the GPU).
//   blocks [0,256)   : qb = (xn @ Wq) * 0.125   (8192x512, K=1024)
//   blocks [256,384) : kvb = media @ Wkv        (2048x1024, K=1024)
// ---------------------------------------------------------------------------
__global__ __launch_bounds__(256, 2) void qkv_gemm(const u16* __restrict__ xn,
                                                   const u16* __restrict__ wqt,
                                                   u16* __restrict__ qb,
                                                   const u16* __restrict__ mediab,
                                                   const u16* __restrict__ wkvt,
                                                   u16* __restrict__ kvb) {
    __shared__ u16 As[128 * 64];
    __shared__ u16 Bs[128 * 64];
    const int b = blockIdx.x;
    const u16 *A, *Bt; u16* C; int N, row0, col0; float sc;
    if (b < 256) { A = xn;     Bt = wqt;  C = qb;  N = 512;  row0 = (b >> 2) * 128; col0 = (b & 3) * 128; sc = 0.125f; }
    else { int t = b - 256; A = mediab; Bt = wkvt; C = kvb; N = 1024; row0 = (t >> 3) * 128; col0 = (t & 7) * 128; sc = 1.f; }
    gemm_tile_g<0>(As, Bs, A, Bt, (void*)C, N, 1024, row0, col0, sc);
}

// ---------------------------------------------------------------------------
// Output projection: out = ao @ Wo  (8192x1024, K=512), f32 store.
// ---------------------------------------------------------------------------
__global__ __launch_bounds__(256, 2) void o_gemm(const u16* __restrict__ ao,
                                                 const u16* __restrict__ wot,
                                                 float* __restrict__ out) {
    __shared__ u16 As[128 * 64];
    __shared__ u16 Bs[128 * 64];
    gemm_tile_g<1>(As, Bs, ao, wot, (void*)out, 1024, 512,
                   (int)blockIdx.y * 128, (int)blockIdx.x * 128, 1.f);
}

// ---------------------------------------------------------------------------
// MFMA flash attention over COMPACTED keys. Block = 2 waves, QBLK=32
// (16 q-rows/wave), KVBLK=32. Grid (64, 8 heads, 4 batch).
// Q is pre-scaled by 0.125 (folded into qkv_gemm). Index list in LDS.
// ---------------------------------------------------------------------------
__global__ __launch_bounds__(128) void attn_mfma(const u16* __restrict__ qb,
                                                 const u16* __restrict__ kvb,
                                                 const int* __restrict__ idx,
                                                 const int* __restrict__ cnts,
                                                 u16* __restrict__ ao) {
    __shared__ u16 Ks[32][72];      // K tile [j][d]
    __shared__ u16 Vt[64][40];      // V^T tile [d][j]
    __shared__ u16 Pl[2][16][40];   // per-wave P transpose [q][j]
    __shared__ int Is[512];         // compacted key indices
    const int tid = threadIdx.x;
    const int l = tid & 63, w = tid >> 6;
    const int l15 = l & 15, l4 = l >> 4;
    const int h = blockIdx.y, bbi = blockIdx.z;
    const int n0 = blockIdx.x * 32;
    const int cnt = cnts[bbi];
    const int ntile = (cnt + 31) & ~31;
    const int* ib = idx + bbi * 512;
    for (int i = tid; i < ntile; i += 128) Is[i] = ib[i];

    const u16* qp = qb + ((size_t)(bbi * 2048 + n0 + w * 16 + l15)) * 512 + h * 64;
    const bf16x8 qf0 = *(const bf16x8*)(qp + l4 * 8);
    const bf16x8 qf1 = *(const bf16x8*)(qp + 32 + l4 * 8);

    const f32x4 zero = {0.f, 0.f, 0.f, 0.f};
    f32x4 acc[4];
#pragma unroll
    for (int dt = 0; dt < 4; ++dt) acc[dt] = zero;
    float mrun[4] = {-3.0e38f, -3.0e38f, -3.0e38f, -3.0e38f};
    float lrun[4] = {0.f, 0.f, 0.f, 0.f};

    const int kj = tid >> 3, kd = (tid & 7) * 8;
    const int vj = tid & 31, vd = (tid >> 5) * 8;
    const u16* kbase = kvb + ((size_t)bbi * 512) * 1024 + h * 64;

    for (int j0 = 0; j0 < cnt; j0 += 32) {
        __syncthreads();  // first iteration also covers Is writes
#pragma unroll
        for (int p = 0; p < 2; ++p) {
            int r = kj + p * 16;
            int row = Is[j0 + r];
            u16x8 kv_ = *(const u16x8*)(kbase + (size_t)row * 1024 + kd);
            *(u16x8*)(&Ks[r][kd]) = kv_;
        }
        {
            int row = Is[j0 + vj];
#pragma unroll
            for (int p = 0; p < 2; ++p) {
                int d0 = vd + p * 32;
                u16x8 vv = *(const u16x8*)(kbase + (size_t)row * 1024 + 512 + d0);
#pragma unroll
                for (int i = 0; i < 8; ++i) Vt[d0 + i][vj] = vv[i];
            }
        }
        __syncthreads();

        // ---- S = Q K^T (16q x 32j), 4 MFMA ----
        f32x4 s[2];
#pragma unroll
        for (int jt = 0; jt < 2; ++jt) {
            bf16x8 kf0 = *(const bf16x8*)(&Ks[jt * 16 + l15][l4 * 8]);
            bf16x8 kf1 = *(const bf16x8*)(&Ks[jt * 16 + l15][32 + l4 * 8]);
            s[jt] = __builtin_amdgcn_mfma_f32_16x16x32_bf16(qf0, kf0, zero, 0, 0, 0);
            s[jt] = __builtin_amdgcn_mfma_f32_16x16x32_bf16(qf1, kf1, s[jt], 0, 0, 0);
        }
        const float mv0 = (j0 + l15 < cnt) ? 0.f : -3.0e38f;        // tail only
        const float mv1 = (j0 + 16 + l15 < cnt) ? 0.f : -3.0e38f;

        // ---- online softmax per q-row r ----
#pragma unroll
        for (int r = 0; r < 4; ++r) {
            float s0 = s[0][r] + mv0;
            float s1 = s[1][r] + mv1;
            float tmax = fmaxf(s0, s1);
#pragma unroll
            for (int o = 1; o < 16; o <<= 1) tmax = fmaxf(tmax, __shfl_xor(tmax, o, 64));
            float mn = fmaxf(mrun[r], tmax);
            float p0 = (s0 > -1.0e37f) ? __expf(s0 - mn) : 0.f;
            float p1 = (s1 > -1.0e37f) ? __expf(s1 - mn) : 0.f;
            float corr = __expf(mrun[r] - mn);
            mrun[r] = mn;
            float psum = p0 + p1;
#pragma unroll
            for (int o = 1; o < 16; o <<= 1) psum += __shfl_xor(psum, o, 64);
            lrun[r] = lrun[r] * corr + psum;
#pragma unroll
            for (int dt = 0; dt < 4; ++dt) acc[dt][r] *= corr;
            Pl[w][l4 * 4 + r][l15] = f2bf(p0);
            Pl[w][l4 * 4 + r][16 + l15] = f2bf(p1);
        }
        // ---- O += P V (4 MFMA) ----
        bf16x8 pf = *(const bf16x8*)(&Pl[w][l15][l4 * 8]);
#pragma unroll
        for (int dt = 0; dt < 4; ++dt) {
            bf16x8 vf = *(const bf16x8*)(&Vt[dt * 16 + l15][l4 * 8]);
            acc[dt] = __builtin_amdgcn_mfma_f32_16x16x32_bf16(pf, vf, acc[dt], 0, 0, 0);
        }
    }

    float inv[4];
#pragma unroll
    for (int r = 0; r < 4; ++r) inv[r] = (lrun[r] > 0.f) ? (1.f / lrun[r]) : 0.f;
    u16* op = ao + ((size_t)(bbi * 2048 + n0 + w * 16)) * 512 + h * 64;
#pragma unroll
    for (int dt = 0; dt < 4; ++dt)
#pragma unroll
        for (int r = 0; r < 4; ++r)
            op[(size_t)(l4 * 4 + r) * 512 + dt * 16 + l15] = f2bf(acc[dt][r] * inv[r]);
}

// ---------------------------------------------------------------------------
// Inputs: FLOAT32; output d_out: FLOAT32 (32 MB). 4 launches total.
// xn (bf16, 16MB) lives in d_out[0..16MB) (o_gemm overwrites all 32MB).
// ws use ~= 28 MB + 16 KB.
// ---------------------------------------------------------------------------
extern "C" void kernel_launch(void* const* d_in, const int* in_sizes, int n_in,
                              void* d_out, int out_size, void* d_ws, size_t ws_size,
                              hipStream_t stream) {
    const float* x = (const float*)d_in[0];
    const float* media = (const float*)d_in[1];
    const unsigned char* mask = (const unsigned char*)d_in[2];
    const float* ln_g = (const float*)d_in[3];
    const float* ln_b = (const float*)d_in[4];
    const float* Wq = (const float*)d_in[5];
    const float* Wkv = (const float*)d_in[6];
    const float* Wo = (const float*)d_in[7];
    float* out = (float*)d_out;

    char* w = (char*)d_ws;
    unsigned char* mask8 = (unsigned char*)w; w += 4096;
    int* idx = (int*)w;    w += 2048 * 4;
    int* cnts = (int*)w;   w += 256;
    u16* qb = (u16*)w;     w += (size_t)8192 * 512 * 2;
    u16* kvb = (u16*)w;    w += (size_t)2048 * 1024 * 2;
    u16* ao = (u16*)w;     w += (size_t)8192 * 512 * 2;
    u16* mediab = (u16*)w; w += (size_t)2048 * 1024 * 2;
    u16* wqt = (u16*)w;    w += (size_t)512 * 1024 * 2;
    u16* wkvt = (u16*)w;   w += (size_t)1024 * 1024 * 2;
    u16* wot = (u16*)w;    w += (size_t)1024 * 512 * 2;
    u16* xn = (u16*)d_out;

    prep_all<<<3841, 256, 0, stream>>>(x, media, mask, ln_g, ln_b, Wq, Wkv, Wo,
                                       xn, mediab, mask8, idx, cnts, wqt, wkvt, wot);
    qkv_gemm<<<384, 256, 0, stream>>>(xn, wqt, qb, mediab, wkvt, kvb);
    attn_mfma<<<dim3(64, 8, 4), 128, 0, stream>>>(qb, kvb, idx, cnts, ao);
    o_gemm<<<dim3(8, 64), 256, 0, stream>>>(ao, wot, out);
}

// Round 12
// 82.501 us; speedup vs baseline: 5.4793x; 1.0772x over previous
//
#include <hip/hip_runtime.h>
#include <hip/hip_bf16.h>

typedef unsigned short u16;
typedef __attribute__((ext_vector_type(4))) unsigned short u16x4;
typedef __attribute__((ext_vector_type(8))) unsigned short u16x8;
typedef __attribute__((ext_vector_type(8))) short bf16x8;
typedef __attribute__((ext_vector_type(4))) float f32x4;

#define AS1 __attribute__((address_space(1)))
#define AS3 __attribute__((address_space(3)))

__device__ __forceinline__ float b2f(u16 v) {
    return __uint_as_float(((unsigned)v) << 16);
}
__device__ __forceinline__ u16 f2bf(float f) {
    unsigned u = __float_as_uint(f);
    unsigned r = (u + 0x7fffu + ((u >> 16) & 1u)) >> 16;
    return (u16)r;
}

// ---------------------------------------------------------------------------
// prep_all: one launch for all independent preprocessing.
//   blocks [0,2048)    : LayerNorm x -> xn (bf16), 4 rows/block
//   blocks [2048,3072) : media f32 -> bf16
//   blocks [3072,3840) : weight transpose-convert (Wq,Wkv,Wo) -> (N,K) bf16
//   block  3840        : mask detect {bool8,int32,f32} + ballot-compact idx
//                        (idx padded with 0 to a multiple of 64 — KVBLK=64!)
// ---------------------------------------------------------------------------
__global__ __launch_bounds__(256) void prep_all(
    const float* __restrict__ x, const float* __restrict__ media,
    const unsigned char* __restrict__ mask,
    const float* __restrict__ ln_g, const float* __restrict__ ln_b,
    const float* __restrict__ Wq, const float* __restrict__ Wkv,
    const float* __restrict__ Wo,
    u16* __restrict__ xn, u16* __restrict__ mediab,
    unsigned char* __restrict__ mask8, int* __restrict__ idx,
    int* __restrict__ cnts,
    u16* __restrict__ wqt, u16* __restrict__ wkvt, u16* __restrict__ wot) {
    __shared__ u16 T[64][72];
    __shared__ int c0s, c1s;
    const int bid = blockIdx.x, tid = threadIdx.x;

    if (bid < 2048) {  // ---- LayerNorm ----
        const int lane = tid & 63;
        const int row = bid * 4 + (tid >> 6);
        const float* xr = x + (size_t)row * 1024;
        float v[16];
        float sum = 0.f, sq = 0.f;
#pragma unroll
        for (int c = 0; c < 4; ++c) {
            float4 u = ((const float4*)xr)[c * 64 + lane];
            v[c * 4 + 0] = u.x; v[c * 4 + 1] = u.y; v[c * 4 + 2] = u.z; v[c * 4 + 3] = u.w;
            sum += u.x + u.y + u.z + u.w;
            sq += u.x * u.x + u.y * u.y + u.z * u.z + u.w * u.w;
        }
#pragma unroll
        for (int o = 1; o < 64; o <<= 1) {
            sum += __shfl_xor(sum, o, 64);
            sq += __shfl_xor(sq, o, 64);
        }
        float mean = sum * (1.f / 1024.f);
        float var = sq * (1.f / 1024.f) - mean * mean;
        float rs = rsqrtf(var + 1e-5f);
        u16* yr = xn + (size_t)row * 1024;
#pragma unroll
        for (int c = 0; c < 4; ++c) {
            float4 ug = ((const float4*)ln_g)[c * 64 + lane];
            float4 ub = ((const float4*)ln_b)[c * 64 + lane];
            u16x4 o;
            o[0] = f2bf((v[c * 4 + 0] - mean) * rs * ug.x + ub.x);
            o[1] = f2bf((v[c * 4 + 1] - mean) * rs * ug.y + ub.y);
            o[2] = f2bf((v[c * 4 + 2] - mean) * rs * ug.z + ub.z);
            o[3] = f2bf((v[c * 4 + 3] - mean) * rs * ug.w + ub.w);
            *(u16x4*)(yr + c * 256 + lane * 4) = o;
        }
    } else if (bid < 3072) {  // ---- media f32->bf16 ----
        int i = (bid - 2048) * 256 + tid;
        float4 a = ((const float4*)media)[i * 2];
        float4 b = ((const float4*)media)[i * 2 + 1];
        u16x8 o;
        o[0] = f2bf(a.x); o[1] = f2bf(a.y); o[2] = f2bf(a.z); o[3] = f2bf(a.w);
        o[4] = f2bf(b.x); o[5] = f2bf(b.y); o[6] = f2bf(b.z); o[7] = f2bf(b.w);
        ((u16x8*)mediab)[i] = o;
    } else if (bid < 3840) {  // ---- weight transpose-convert ----
        const int t = bid - 3072;
        const int z = t >> 8, rem = t & 255;
        const float* in; u16* out; int K, N;
        if (z == 0)      { in = Wq;  out = wqt;  K = 1024; N = 512; }
        else if (z == 1) { in = Wkv; out = wkvt; K = 1024; N = 1024; }
        else             { in = Wo;  out = wot;  K = 512;  N = 1024; }
        const int k0 = (rem >> 4) * 64, n0 = (rem & 15) * 64;
        if (k0 >= K || n0 >= N) return;
#pragma unroll
        for (int p = 0; p < 4; ++p) {
            int kr = p * 16 + (tid >> 4);
            float4 u = *(const float4*)(in + (size_t)(k0 + kr) * N + n0 + (tid & 15) * 4);
            u16x4 o4;
            o4[0] = f2bf(u.x); o4[1] = f2bf(u.y); o4[2] = f2bf(u.z); o4[3] = f2bf(u.w);
            *(u16x4*)(&T[kr][(tid & 15) * 4]) = o4;
        }
        __syncthreads();
        const int n = tid >> 2, kc = (tid & 3) * 16;
#pragma unroll
        for (int hh = 0; hh < 2; ++hh) {
            u16x8 o;
#pragma unroll
            for (int i = 0; i < 8; ++i) o[i] = T[kc + hh * 8 + i][n];
            *(u16x8*)(out + (size_t)(n0 + n) * K + k0 + kc + hh * 8) = o;
        }
    } else {  // ---- mask detect + compact ----
        if (tid == 0) { c0s = 0; c1s = 0; }
        __syncthreads();
        int a0 = 0, a1 = 0;
        for (int i = tid; i < 2048; i += 256) {
            if (mask[i]) {
                int cl = i & 3;
                if (cl == 0) a0 = 1;
                else if (cl == 1) a1 = 1;
            }
        }
        if (a0) atomicOr(&c0s, 1);
        if (a1) atomicOr(&c1s, 1);
        __syncthreads();
        int fmt = c1s ? 1 : (c0s ? 0 : 2);  // 1=bool8, 0=int32, 2=float32
        for (int e = tid; e < 2048; e += 256) {
            unsigned char v;
            if (fmt == 1)      v = (mask[e] != 0);
            else if (fmt == 0) v = (((const int*)mask)[e] != 0);
            else               v = (((const float*)mask)[e] != 0.f);
            mask8[e] = v;
        }
        __syncthreads();
        const int wv = tid >> 6, l = tid & 63;
        int off = 0;
#pragma unroll
        for (int c = 0; c < 8; ++c) {
            int key = c * 64 + l;
            bool v = mask8[wv * 512 + key] != 0;
            unsigned long long m = __ballot(v);
            int rank = __popcll(m & ((1ull << l) - 1ull));
            if (v) idx[wv * 512 + off + rank] = key;
            off += __popcll(m);
        }
        if (l == 0) cnts[wv] = off;
        int nt = (off + 63) & ~63;          // r11 fault fix: pad to KVBLK=64
        for (int p = off + l; p < nt; p += 64) idx[wv * 512 + p] = 0;
    }
}

// ---------------------------------------------------------------------------
// GEMM tile body with global_load_lds staging + XOR-swizzled LDS.
// C(128x128 tile) = A(MxK) @ Bt(NxK)^T, BK=64, 4 waves.
// ---------------------------------------------------------------------------
template <int OUTF32>
__device__ __forceinline__ void gemm_tile_g(u16* As, u16* Bs,
                                            const u16* __restrict__ A,
                                            const u16* __restrict__ Bt,
                                            void* __restrict__ Cv,
                                            int N, int K, int row0, int col0,
                                            float scale) {
    const int tid = threadIdx.x;
    const int l = tid & 63, w = tid >> 6;
    const int l15 = l & 15, l4 = l >> 4;
    const int wm = w >> 1, wn = w & 1;
    const int lr = l >> 3;                 // row-within-8 for staging
    const int cs = ((l & 7) ^ lr) * 8;     // pre-swizzled source slot (elems)

    f32x4 zero = {0.f, 0.f, 0.f, 0.f};
    f32x4 acc[4][4];
#pragma unroll
    for (int i = 0; i < 4; ++i)
#pragma unroll
        for (int j = 0; j < 4; ++j) acc[i][j] = zero;

    const int rsw = l15 & 7;               // row&7 for all fragment rows

    for (int k0 = 0; k0 < K; k0 += 64) {
        __syncthreads();
#pragma unroll
        for (int i = 0; i < 4; ++i) {
            int r = w * 32 + i * 8;        // wave-uniform 8-row group
            __builtin_amdgcn_global_load_lds(
                (const AS1 void*)(A + (size_t)(row0 + r + lr) * K + k0 + cs),
                (AS3 void*)(As + r * 64), 16, 0, 0);
            __builtin_amdgcn_global_load_lds(
                (const AS1 void*)(Bt + (size_t)(col0 + r + lr) * K + k0 + cs),
                (AS3 void*)(Bs + r * 64), 16, 0, 0);
        }
        __syncthreads();
#pragma unroll
        for (int h = 0; h < 2; ++h) {      // two K=32 sub-steps
            bf16x8 aF[4], bF[4];
#pragma unroll
            for (int m = 0; m < 4; ++m) {
                int s = (h * 4 + l4) ^ rsw;             // swizzled slot
                aF[m] = *(const bf16x8*)(As + (wm * 64 + m * 16 + l15) * 64 + s * 8);
                bF[m] = *(const bf16x8*)(Bs + (wn * 64 + m * 16 + l15) * 64 + s * 8);
            }
#pragma unroll
            for (int m = 0; m < 4; ++m)
#pragma unroll
                for (int n = 0; n < 4; ++n)
                    acc[m][n] = __builtin_amdgcn_mfma_f32_16x16x32_bf16(aF[m], bF[n], acc[m][n], 0, 0, 0);
        }
    }
#pragma unroll
    for (int m = 0; m < 4; ++m)
#pragma unroll
        for (int n = 0; n < 4; ++n) {
            int row = row0 + wm * 64 + m * 16 + l4 * 4;
            int col = col0 + wn * 64 + n * 16 + l15;
#pragma unroll
            for (int r = 0; r < 4; ++r) {
                float vv = acc[m][n][r] * scale;
                if (OUTF32)
                    ((float*)Cv)[(size_t)(row + r) * N + col] = vv;
                else
                    ((u16*)Cv)[(size_t)(row + r) * N + col] = f2bf(vv);
            }
        }
}

// ---------------------------------------------------------------------------
// Merged Q + KV projection GEMM (384 blocks fills the GPU).
// ---------------------------------------------------------------------------
__global__ __launch_bounds__(256, 2) void qkv_gemm(const u16* __restrict__ xn,
                                                   const u16* __restrict__ wqt,
                                                   u16* __restrict__ qb,
                                                   const u16* __restrict__ mediab,
                                                   const u16* __restrict__ wkvt,
                                                   u16* __restrict__ kvb) {
    __shared__ u16 As[128 * 64];
    __shared__ u16 Bs[128 * 64];
    const int b = blockIdx.x;
    const u16 *A, *Bt; u16* C; int N, row0, col0; float sc;
    if (b < 256) { A = xn;     Bt = wqt;  C = qb;  N = 512;  row0 = (b >> 2) * 128; col0 = (b & 3) * 128; sc = 0.125f; }
    else { int t = b - 256; A = mediab; Bt = wkvt; C = kvb; N = 1024; row0 = (t >> 3) * 128; col0 = (t & 7) * 128; sc = 1.f; }
    gemm_tile_g<0>(As, Bs, A, Bt, (void*)C, N, 1024, row0, col0, sc);
}

// ---------------------------------------------------------------------------
// Output projection: out = ao @ Wo  (8192x1024, K=512), f32 store.
// ---------------------------------------------------------------------------
__global__ __launch_bounds__(256, 2) void o_gemm(const u16* __restrict__ ao,
                                                 const u16* __restrict__ wot,
                                                 float* __restrict__ out) {
    __shared__ u16 As[128 * 64];
    __shared__ u16 Bs[128 * 64];
    gemm_tile_g<1>(As, Bs, ao, wot, (void*)out, 1024, 512,
                   (int)blockIdx.y * 128, (int)blockIdx.x * 128, 1.f);
}

// ---------------------------------------------------------------------------
// MFMA flash attention over COMPACTED keys. Block = 4 waves (256 thr),
// QBLK=64 (16 q-rows/wave), KVBLK=64. Grid (32, 8 heads, 4 batch).
// idx is 64-padded (prep_all), so all Is[j0..j0+63] gathers are in-bounds;
// tail scores are masked via mv[jt] (expf(-3e38 - mn) == 0).
// ---------------------------------------------------------------------------
__global__ __launch_bounds__(256) void attn_mfma(const u16* __restrict__ qb,
                                                 const u16* __restrict__ kvb,
                                                 const int* __restrict__ idx,
                                                 const int* __restrict__ cnts,
                                                 u16* __restrict__ ao) {
    __shared__ u16 Ks[64][72];      // K tile [j][d]
    __shared__ u16 Vt[64][72];      // V^T tile [d][j]
    __shared__ u16 Pl[4][16][72];   // per-wave P [q][j]
    __shared__ int Is[512];         // compacted key indices
    const int tid = threadIdx.x;
    const int l = tid & 63, w = tid >> 6;
    const int l15 = l & 15, l4 = l >> 4;
    const int h = blockIdx.y, bbi = blockIdx.z;
    const int n0 = blockIdx.x * 64;
    const int cnt = cnts[bbi];
    const int ntile = (cnt + 63) & ~63;   // 64-aligned (matches prep padding)
    const int* ib = idx + bbi * 512;
    for (int i = tid; i < ntile; i += 256) Is[i] = ib[i];

    const u16* qp = qb + ((size_t)(bbi * 2048 + n0 + w * 16 + l15)) * 512 + h * 64;
    const bf16x8 qf0 = *(const bf16x8*)(qp + l4 * 8);
    const bf16x8 qf1 = *(const bf16x8*)(qp + 32 + l4 * 8);

    const f32x4 zero = {0.f, 0.f, 0.f, 0.f};
    f32x4 acc[4];
#pragma unroll
    for (int dt = 0; dt < 4; ++dt) acc[dt] = zero;
    float mrun[4] = {-3.0e38f, -3.0e38f, -3.0e38f, -3.0e38f};
    float lrun[4] = {0.f, 0.f, 0.f, 0.f};

    const int kj = tid >> 3, kd = (tid & 7) * 8;
    const int vj = tid & 63, vd = (tid >> 6) * 16;
    const u16* kbase = kvb + ((size_t)bbi * 512) * 1024 + h * 64;

    for (int j0 = 0; j0 < cnt; j0 += 64) {
        __syncthreads();  // first iteration also covers Is writes
#pragma unroll
        for (int p = 0; p < 2; ++p) {
            int r = kj + p * 32;
            int row = Is[j0 + r];
            u16x8 kv_ = *(const u16x8*)(kbase + (size_t)row * 1024 + kd);
            *(u16x8*)(&Ks[r][kd]) = kv_;
        }
        {
            int row = Is[j0 + vj];
#pragma unroll
            for (int p = 0; p < 2; ++p) {
                u16x8 vv = *(const u16x8*)(kbase + (size_t)row * 1024 + 512 + vd + p * 8);
#pragma unroll
                for (int i = 0; i < 8; ++i) Vt[vd + p * 8 + i][vj] = vv[i];
            }
        }
        __syncthreads();

        // ---- S = Q K^T (16q x 64j), 8 MFMA ----
        f32x4 s[4];
        float mv[4];
#pragma unroll
        for (int jt = 0; jt < 4; ++jt) {
            bf16x8 kf0 = *(const bf16x8*)(&Ks[jt * 16 + l15][l4 * 8]);
            bf16x8 kf1 = *(const bf16x8*)(&Ks[jt * 16 + l15][32 + l4 * 8]);
            s[jt] = __builtin_amdgcn_mfma_f32_16x16x32_bf16(qf0, kf0, zero, 0, 0, 0);
            s[jt] = __builtin_amdgcn_mfma_f32_16x16x32_bf16(qf1, kf1, s[jt], 0, 0, 0);
            mv[jt] = (j0 + jt * 16 + l15 < cnt) ? 0.f : -3.0e38f;
        }

        // ---- online softmax per q-row r (one 16-lane reduce per 64 keys) ----
#pragma unroll
        for (int r = 0; r < 4; ++r) {
            float s0 = s[0][r] + mv[0];
            float s1 = s[1][r] + mv[1];
            float s2 = s[2][r] + mv[2];
            float s3 = s[3][r] + mv[3];
            float tmax = fmaxf(fmaxf(s0, s1), fmaxf(s2, s3));
#pragma unroll
            for (int o = 1; o < 16; o <<= 1) tmax = fmaxf(tmax, __shfl_xor(tmax, o, 64));
            float mn = fmaxf(mrun[r], tmax);
            float p0 = __expf(s0 - mn);
            float p1 = __expf(s1 - mn);
            float p2 = __expf(s2 - mn);
            float p3 = __expf(s3 - mn);
            float corr = __expf(mrun[r] - mn);
            mrun[r] = mn;
            float psum = (p0 + p1) + (p2 + p3);
#pragma unroll
            for (int o = 1; o < 16; o <<= 1) psum += __shfl_xor(psum, o, 64);
            lrun[r] = lrun[r] * corr + psum;
#pragma unroll
            for (int dt = 0; dt < 4; ++dt) acc[dt][r] *= corr;
            Pl[w][l4 * 4 + r][l15] = f2bf(p0);
            Pl[w][l4 * 4 + r][16 + l15] = f2bf(p1);
            Pl[w][l4 * 4 + r][32 + l15] = f2bf(p2);
            Pl[w][l4 * 4 + r][48 + l15] = f2bf(p3);
        }
        // ---- O += P V (8 MFMA) ----
        bf16x8 pf0 = *(const bf16x8*)(&Pl[w][l15][l4 * 8]);
        bf16x8 pf1 = *(const bf16x8*)(&Pl[w][l15][32 + l4 * 8]);
#pragma unroll
        for (int dt = 0; dt < 4; ++dt) {
            bf16x8 vf0 = *(const bf16x8*)(&Vt[dt * 16 + l15][l4 * 8]);
            bf16x8 vf1 = *(const bf16x8*)(&Vt[dt * 16 + l15][32 + l4 * 8]);
            acc[dt] = __builtin_amdgcn_mfma_f32_16x16x32_bf16(pf0, vf0, acc[dt], 0, 0, 0);
            acc[dt] = __builtin_amdgcn_mfma_f32_16x16x32_bf16(pf1, vf1, acc[dt], 0, 0, 0);
        }
    }

    float inv[4];
#pragma unroll
    for (int r = 0; r < 4; ++r) inv[r] = (lrun[r] > 0.f) ? (1.f / lrun[r]) : 0.f;
    u16* op = ao + ((size_t)(bbi * 2048 + n0 + w * 16)) * 512 + h * 64;
#pragma unroll
    for (int dt = 0; dt < 4; ++dt)
#pragma unroll
        for (int r = 0; r < 4; ++r)
            op[(size_t)(l4 * 4 + r) * 512 + dt * 16 + l15] = f2bf(acc[dt][r] * inv[r]);
}

// ---------------------------------------------------------------------------
// Inputs: FLOAT32; output d_out: FLOAT32 (32 MB). 4 launches total.
// xn (bf16, 16MB) lives in d_out[0..16MB) (o_gemm overwrites all 32MB).
// ws use ~= 28 MB + 16 KB.
// ---------------------------------------------------------------------------
extern "C" void kernel_launch(void* const* d_in, const int* in_sizes, int n_in,
                              void* d_out, int out_size, void* d_ws, size_t ws_size,
                              hipStream_t stream) {
    const float* x = (const float*)d_in[0];
    const float* media = (const float*)d_in[1];
    const unsigned char* mask = (const unsigned char*)d_in[2];
    const float* ln_g = (const float*)d_in[3];
    const float* ln_b = (const float*)d_in[4];
    const float* Wq = (const float*)d_in[5];
    const float* Wkv = (const float*)d_in[6];
    const float* Wo = (const float*)d_in[7];
    float* out = (float*)d_out;

    char* w = (char*)d_ws;
    unsigned char* mask8 = (unsigned char*)w; w += 4096;
    int* idx = (int*)w;    w += 2048 * 4;
    int* cnts = (int*)w;   w += 256;
    u16* qb = (u16*)w;     w += (size_t)8192 * 512 * 2;
    u16* kvb = (u16*)w;    w += (size_t)2048 * 1024 * 2;
    u16* ao = (u16*)w;     w += (size_t)8192 * 512 * 2;
    u16* mediab = (u16*)w; w += (size_t)2048 * 1024 * 2;
    u16* wqt = (u16*)w;    w += (size_t)512 * 1024 * 2;
    u16* wkvt = (u16*)w;   w += (size_t)1024 * 1024 * 2;
    u16* wot = (u16*)w;    w += (size_t)1024 * 512 * 2;
    u16* xn = (u16*)d_out;

    prep_all<<<3841, 256, 0, stream>>>(x, media, mask, ln_g, ln_b, Wq, Wkv, Wo,
                                       xn, mediab, mask8, idx, cnts, wqt, wkvt, wot);
    qkv_gemm<<<384, 256, 0, stream>>>(xn, wqt, qb, mediab, wkvt, kvb);
    attn_mfma<<<dim3(32, 8, 4), 256, 0, stream>>>(qb, kvb, idx, cnts, ao);
    o_gemm<<<dim3(8, 64), 256, 0, stream>>>(ao, wot, out);
}

// Round 13
// 77.830 us; speedup vs baseline: 5.8082x; 1.0600x over previous
//
#include <hip/hip_runtime.h>
#include <hip/hip_bf16.h>

typedef unsigned short u16;
typedef __attribute__((ext_vector_type(4))) unsigned short u16x4;
typedef __attribute__((ext_vector_type(8))) unsigned short u16x8;
typedef __attribute__((ext_vector_type(8))) short bf16x8;
typedef __attribute__((ext_vector_type(4))) float f32x4;

#define AS1 __attribute__((address_space(1)))
#define AS3 __attribute__((address_space(3)))

__device__ __forceinline__ float b2f(u16 v) {
    return __uint_as_float(((unsigned)v) << 16);
}
__device__ __forceinline__ u16 f2bf(float f) {
    unsigned u = __float_as_uint(f);
    unsigned r = (u + 0x7fffu + ((u >> 16) & 1u)) >> 16;
    return (u16)r;
}

// ---------------------------------------------------------------------------
// prep_all: one launch for all independent preprocessing.
//   blocks [0,2048)    : LayerNorm x -> xn (bf16), 4 rows/block
//   blocks [2048,3072) : media f32 -> bf16
//   blocks [3072,3840) : weight transpose-convert (Wq,Wkv,Wo) -> (N,K) bf16
//   block  3840        : mask detect {bool8,int32,f32} + ballot-compact idx
//                        (idx padded with 0 to a multiple of 64 — KVBLK=64)
// ---------------------------------------------------------------------------
__global__ __launch_bounds__(256) void prep_all(
    const float* __restrict__ x, const float* __restrict__ media,
    const unsigned char* __restrict__ mask,
    const float* __restrict__ ln_g, const float* __restrict__ ln_b,
    const float* __restrict__ Wq, const float* __restrict__ Wkv,
    const float* __restrict__ Wo,
    u16* __restrict__ xn, u16* __restrict__ mediab,
    unsigned char* __restrict__ mask8, int* __restrict__ idx,
    int* __restrict__ cnts,
    u16* __restrict__ wqt, u16* __restrict__ wkvt, u16* __restrict__ wot) {
    __shared__ u16 T[64][72];
    __shared__ int c0s, c1s;
    const int bid = blockIdx.x, tid = threadIdx.x;

    if (bid < 2048) {  // ---- LayerNorm ----
        const int lane = tid & 63;
        const int row = bid * 4 + (tid >> 6);
        const float* xr = x + (size_t)row * 1024;
        float v[16];
        float sum = 0.f, sq = 0.f;
#pragma unroll
        for (int c = 0; c < 4; ++c) {
            float4 u = ((const float4*)xr)[c * 64 + lane];
            v[c * 4 + 0] = u.x; v[c * 4 + 1] = u.y; v[c * 4 + 2] = u.z; v[c * 4 + 3] = u.w;
            sum += u.x + u.y + u.z + u.w;
            sq += u.x * u.x + u.y * u.y + u.z * u.z + u.w * u.w;
        }
#pragma unroll
        for (int o = 1; o < 64; o <<= 1) {
            sum += __shfl_xor(sum, o, 64);
            sq += __shfl_xor(sq, o, 64);
        }
        float mean = sum * (1.f / 1024.f);
        float var = sq * (1.f / 1024.f) - mean * mean;
        float rs = rsqrtf(var + 1e-5f);
        u16* yr = xn + (size_t)row * 1024;
#pragma unroll
        for (int c = 0; c < 4; ++c) {
            float4 ug = ((const float4*)ln_g)[c * 64 + lane];
            float4 ub = ((const float4*)ln_b)[c * 64 + lane];
            u16x4 o;
            o[0] = f2bf((v[c * 4 + 0] - mean) * rs * ug.x + ub.x);
            o[1] = f2bf((v[c * 4 + 1] - mean) * rs * ug.y + ub.y);
            o[2] = f2bf((v[c * 4 + 2] - mean) * rs * ug.z + ub.z);
            o[3] = f2bf((v[c * 4 + 3] - mean) * rs * ug.w + ub.w);
            *(u16x4*)(yr + c * 256 + lane * 4) = o;
        }
    } else if (bid < 3072) {  // ---- media f32->bf16 ----
        int i = (bid - 2048) * 256 + tid;
        float4 a = ((const float4*)media)[i * 2];
        float4 b = ((const float4*)media)[i * 2 + 1];
        u16x8 o;
        o[0] = f2bf(a.x); o[1] = f2bf(a.y); o[2] = f2bf(a.z); o[3] = f2bf(a.w);
        o[4] = f2bf(b.x); o[5] = f2bf(b.y); o[6] = f2bf(b.z); o[7] = f2bf(b.w);
        ((u16x8*)mediab)[i] = o;
    } else if (bid < 3840) {  // ---- weight transpose-convert ----
        const int t = bid - 3072;
        const int z = t >> 8, rem = t & 255;
        const float* in; u16* out; int K, N;
        if (z == 0)      { in = Wq;  out = wqt;  K = 1024; N = 512; }
        else if (z == 1) { in = Wkv; out = wkvt; K = 1024; N = 1024; }
        else             { in = Wo;  out = wot;  K = 512;  N = 1024; }
        const int k0 = (rem >> 4) * 64, n0 = (rem & 15) * 64;
        if (k0 >= K || n0 >= N) return;
#pragma unroll
        for (int p = 0; p < 4; ++p) {
            int kr = p * 16 + (tid >> 4);
            float4 u = *(const float4*)(in + (size_t)(k0 + kr) * N + n0 + (tid & 15) * 4);
            u16x4 o4;
            o4[0] = f2bf(u.x); o4[1] = f2bf(u.y); o4[2] = f2bf(u.z); o4[3] = f2bf(u.w);
            *(u16x4*)(&T[kr][(tid & 15) * 4]) = o4;
        }
        __syncthreads();
        const int n = tid >> 2, kc = (tid & 3) * 16;
#pragma unroll
        for (int hh = 0; hh < 2; ++hh) {
            u16x8 o;
#pragma unroll
            for (int i = 0; i < 8; ++i) o[i] = T[kc + hh * 8 + i][n];
            *(u16x8*)(out + (size_t)(n0 + n) * K + k0 + kc + hh * 8) = o;
        }
    } else {  // ---- mask detect + compact ----
        if (tid == 0) { c0s = 0; c1s = 0; }
        __syncthreads();
        int a0 = 0, a1 = 0;
        for (int i = tid; i < 2048; i += 256) {
            if (mask[i]) {
                int cl = i & 3;
                if (cl == 0) a0 = 1;
                else if (cl == 1) a1 = 1;
            }
        }
        if (a0) atomicOr(&c0s, 1);
        if (a1) atomicOr(&c1s, 1);
        __syncthreads();
        int fmt = c1s ? 1 : (c0s ? 0 : 2);  // 1=bool8, 0=int32, 2=float32
        for (int e = tid; e < 2048; e += 256) {
            unsigned char v;
            if (fmt == 1)      v = (mask[e] != 0);
            else if (fmt == 0) v = (((const int*)mask)[e] != 0);
            else               v = (((const float*)mask)[e] != 0.f);
            mask8[e] = v;
        }
        __syncthreads();
        const int wv = tid >> 6, l = tid & 63;
        int off = 0;
#pragma unroll
        for (int c = 0; c < 8; ++c) {
            int key = c * 64 + l;
            bool v = mask8[wv * 512 + key] != 0;
            unsigned long long m = __ballot(v);
            int rank = __popcll(m & ((1ull << l) - 1ull));
            if (v) idx[wv * 512 + off + rank] = key;
            off += __popcll(m);
        }
        if (l == 0) cnts[wv] = off;
        int nt = (off + 63) & ~63;          // pad to KVBLK=64
        for (int p = off + l; p < nt; p += 64) idx[wv * 512 + p] = 0;
    }
}

// ---------------------------------------------------------------------------
// GEMM tile body with global_load_lds staging + XOR-swizzled LDS.
// C(128x128 tile) = A(MxK) @ Bt(NxK)^T, BK=64, 4 waves.
// ---------------------------------------------------------------------------
template <int OUTF32>
__device__ __forceinline__ void gemm_tile_g(u16* As, u16* Bs,
                                            const u16* __restrict__ A,
                                            const u16* __restrict__ Bt,
                                            void* __restrict__ Cv,
                                            int N, int K, int row0, int col0,
                                            float scale) {
    const int tid = threadIdx.x;
    const int l = tid & 63, w = tid >> 6;
    const int l15 = l & 15, l4 = l >> 4;
    const int wm = w >> 1, wn = w & 1;
    const int lr = l >> 3;                 // row-within-8 for staging
    const int cs = ((l & 7) ^ lr) * 8;     // pre-swizzled source slot (elems)

    f32x4 zero = {0.f, 0.f, 0.f, 0.f};
    f32x4 acc[4][4];
#pragma unroll
    for (int i = 0; i < 4; ++i)
#pragma unroll
        for (int j = 0; j < 4; ++j) acc[i][j] = zero;

    const int rsw = l15 & 7;               // row&7 for all fragment rows

    for (int k0 = 0; k0 < K; k0 += 64) {
        __syncthreads();
#pragma unroll
        for (int i = 0; i < 4; ++i) {
            int r = w * 32 + i * 8;        // wave-uniform 8-row group
            __builtin_amdgcn_global_load_lds(
                (const AS1 void*)(A + (size_t)(row0 + r + lr) * K + k0 + cs),
                (AS3 void*)(As + r * 64), 16, 0, 0);
            __builtin_amdgcn_global_load_lds(
                (const AS1 void*)(Bt + (size_t)(col0 + r + lr) * K + k0 + cs),
                (AS3 void*)(Bs + r * 64), 16, 0, 0);
        }
        __syncthreads();
#pragma unroll
        for (int h = 0; h < 2; ++h) {      // two K=32 sub-steps
            bf16x8 aF[4], bF[4];
#pragma unroll
            for (int m = 0; m < 4; ++m) {
                int s = (h * 4 + l4) ^ rsw;             // swizzled slot
                aF[m] = *(const bf16x8*)(As + (wm * 64 + m * 16 + l15) * 64 + s * 8);
                bF[m] = *(const bf16x8*)(Bs + (wn * 64 + m * 16 + l15) * 64 + s * 8);
            }
#pragma unroll
            for (int m = 0; m < 4; ++m)
#pragma unroll
                for (int n = 0; n < 4; ++n)
                    acc[m][n] = __builtin_amdgcn_mfma_f32_16x16x32_bf16(aF[m], bF[n], acc[m][n], 0, 0, 0);
        }
    }
#pragma unroll
    for (int m = 0; m < 4; ++m)
#pragma unroll
        for (int n = 0; n < 4; ++n) {
            int row = row0 + wm * 64 + m * 16 + l4 * 4;
            int col = col0 + wn * 64 + n * 16 + l15;
#pragma unroll
            for (int r = 0; r < 4; ++r) {
                float vv = acc[m][n][r] * scale;
                if (OUTF32)
                    ((float*)Cv)[(size_t)(row + r) * N + col] = vv;
                else
                    ((u16*)Cv)[(size_t)(row + r) * N + col] = f2bf(vv);
            }
        }
}

// ---------------------------------------------------------------------------
// Merged Q + KV projection GEMM (384 blocks fills the GPU).
// ---------------------------------------------------------------------------
__global__ __launch_bounds__(256, 2) void qkv_gemm(const u16* __restrict__ xn,
                                                   const u16* __restrict__ wqt,
                                                   u16* __restrict__ qb,
                                                   const u16* __restrict__ mediab,
                                                   const u16* __restrict__ wkvt,
                                                   u16* __restrict__ kvb) {
    __shared__ u16 As[128 * 64];
    __shared__ u16 Bs[128 * 64];
    const int b = blockIdx.x;
    const u16 *A, *Bt; u16* C; int N, row0, col0; float sc;
    if (b < 256) { A = xn;     Bt = wqt;  C = qb;  N = 512;  row0 = (b >> 2) * 128; col0 = (b & 3) * 128; sc = 0.125f; }
    else { int t = b - 256; A = mediab; Bt = wkvt; C = kvb; N = 1024; row0 = (t >> 3) * 128; col0 = (t & 7) * 128; sc = 1.f; }
    gemm_tile_g<0>(As, Bs, A, Bt, (void*)C, N, 1024, row0, col0, sc);
}

// ---------------------------------------------------------------------------
// Output projection: out = ao @ Wo  (8192x1024, K=512), f32 store.
// ---------------------------------------------------------------------------
__global__ __launch_bounds__(256, 2) void o_gemm(const u16* __restrict__ ao,
                                                 const u16* __restrict__ wot,
                                                 float* __restrict__ out) {
    __shared__ u16 As[128 * 64];
    __shared__ u16 Bs[128 * 64];
    gemm_tile_g<1>(As, Bs, ao, wot, (void*)out, 1024, 512,
                   (int)blockIdx.y * 128, (int)blockIdx.x * 128, 1.f);
}

// ---------------------------------------------------------------------------
// MFMA flash attention over COMPACTED keys. Block = 4 waves (256 thr),
// QBLK=64 (16 q-rows/wave), KVBLK=64. Grid (32, 8 heads, 4 batch).
// Defer-max (T13): per tile one wave-wide __all test; fast path (common after
// tile 0) skips max-reduce, acc rescale and mrun update (P bounded by e^8).
// lrun is a PER-LANE partial, cross-lane-reduced once in the epilogue.
// Slow path (tile 0 + rare max growth) is the full online-softmax update.
// ---------------------------------------------------------------------------
__global__ __launch_bounds__(256) void attn_mfma(const u16* __restrict__ qb,
                                                 const u16* __restrict__ kvb,
                                                 const int* __restrict__ idx,
                                                 const int* __restrict__ cnts,
                                                 u16* __restrict__ ao) {
    __shared__ u16 Ks[64][72];      // K tile [j][d]
    __shared__ u16 Vt[64][72];      // V^T tile [d][j]
    __shared__ u16 Pl[4][16][72];   // per-wave P [q][j]
    __shared__ int Is[512];         // compacted key indices
    const int tid = threadIdx.x;
    const int l = tid & 63, w = tid >> 6;
    const int l15 = l & 15, l4 = l >> 4;
    const int h = blockIdx.y, bbi = blockIdx.z;
    const int n0 = blockIdx.x * 64;
    const int cnt = cnts[bbi];
    const int ntile = (cnt + 63) & ~63;   // 64-aligned (matches prep padding)
    const int* ib = idx + bbi * 512;
    for (int i = tid; i < ntile; i += 256) Is[i] = ib[i];

    const u16* qp = qb + ((size_t)(bbi * 2048 + n0 + w * 16 + l15)) * 512 + h * 64;
    const bf16x8 qf0 = *(const bf16x8*)(qp + l4 * 8);
    const bf16x8 qf1 = *(const bf16x8*)(qp + 32 + l4 * 8);

    const f32x4 zero = {0.f, 0.f, 0.f, 0.f};
    f32x4 acc[4];
#pragma unroll
    for (int dt = 0; dt < 4; ++dt) acc[dt] = zero;
    float mrun[4] = {-3.0e38f, -3.0e38f, -3.0e38f, -3.0e38f};
    float lrun[4] = {0.f, 0.f, 0.f, 0.f};   // per-lane partial denominator

    const int kj = tid >> 3, kd = (tid & 7) * 8;
    const int vj = tid & 63, vd = (tid >> 6) * 16;
    const u16* kbase = kvb + ((size_t)bbi * 512) * 1024 + h * 64;

    for (int j0 = 0; j0 < cnt; j0 += 64) {
        __syncthreads();  // first iteration also covers Is writes
#pragma unroll
        for (int p = 0; p < 2; ++p) {
            int r = kj + p * 32;
            int row = Is[j0 + r];
            u16x8 kv_ = *(const u16x8*)(kbase + (size_t)row * 1024 + kd);
            *(u16x8*)(&Ks[r][kd]) = kv_;
        }
        {
            int row = Is[j0 + vj];
#pragma unroll
            for (int p = 0; p < 2; ++p) {
                u16x8 vv = *(const u16x8*)(kbase + (size_t)row * 1024 + 512 + vd + p * 8);
#pragma unroll
                for (int i = 0; i < 8; ++i) Vt[vd + p * 8 + i][vj] = vv[i];
            }
        }
        __syncthreads();

        // ---- S = Q K^T (16q x 64j), 8 MFMA ----
        f32x4 s[4];
        float mv[4];
#pragma unroll
        for (int jt = 0; jt < 4; ++jt) {
            bf16x8 kf0 = *(const bf16x8*)(&Ks[jt * 16 + l15][l4 * 8]);
            bf16x8 kf1 = *(const bf16x8*)(&Ks[jt * 16 + l15][32 + l4 * 8]);
            s[jt] = __builtin_amdgcn_mfma_f32_16x16x32_bf16(qf0, kf0, zero, 0, 0, 0);
            s[jt] = __builtin_amdgcn_mfma_f32_16x16x32_bf16(qf1, kf1, s[jt], 0, 0, 0);
            mv[jt] = (j0 + jt * 16 + l15 < cnt) ? 0.f : -3.0e38f;
        }

        // ---- defer-max test (one ballot for the whole wave) ----
        float sv[4][4];   // [r][jt]
        float pmax[4];
        bool cond = true;
#pragma unroll
        for (int r = 0; r < 4; ++r) {
#pragma unroll
            for (int jt = 0; jt < 4; ++jt) sv[r][jt] = s[jt][r] + mv[jt];
            pmax[r] = fmaxf(fmaxf(sv[r][0], sv[r][1]), fmaxf(sv[r][2], sv[r][3]));
            cond = cond && (pmax[r] <= mrun[r] + 8.f);
        }
        if (__all(cond)) {
            // ---- fast path: no reduction, no rescale ----
#pragma unroll
            for (int r = 0; r < 4; ++r) {
                float p0 = __expf(sv[r][0] - mrun[r]);
                float p1 = __expf(sv[r][1] - mrun[r]);
                float p2 = __expf(sv[r][2] - mrun[r]);
                float p3 = __expf(sv[r][3] - mrun[r]);
                lrun[r] += (p0 + p1) + (p2 + p3);
                Pl[w][l4 * 4 + r][l15] = f2bf(p0);
                Pl[w][l4 * 4 + r][16 + l15] = f2bf(p1);
                Pl[w][l4 * 4 + r][32 + l15] = f2bf(p2);
                Pl[w][l4 * 4 + r][48 + l15] = f2bf(p3);
            }
        } else {
            // ---- slow path: full online-softmax update ----
#pragma unroll
            for (int r = 0; r < 4; ++r) {
                float tmax = pmax[r];
#pragma unroll
                for (int o = 1; o < 16; o <<= 1) tmax = fmaxf(tmax, __shfl_xor(tmax, o, 64));
                float mn = fmaxf(mrun[r], tmax);
                float corr = __expf(mrun[r] - mn);
                mrun[r] = mn;
                float p0 = __expf(sv[r][0] - mn);
                float p1 = __expf(sv[r][1] - mn);
                float p2 = __expf(sv[r][2] - mn);
                float p3 = __expf(sv[r][3] - mn);
                lrun[r] = lrun[r] * corr + (p0 + p1) + (p2 + p3);
#pragma unroll
                for (int dt = 0; dt < 4; ++dt) acc[dt][r] *= corr;
                Pl[w][l4 * 4 + r][l15] = f2bf(p0);
                Pl[w][l4 * 4 + r][16 + l15] = f2bf(p1);
                Pl[w][l4 * 4 + r][32 + l15] = f2bf(p2);
                Pl[w][l4 * 4 + r][48 + l15] = f2bf(p3);
            }
        }
        // ---- O += P V (8 MFMA) ----
        bf16x8 pf0 = *(const bf16x8*)(&Pl[w][l15][l4 * 8]);
        bf16x8 pf1 = *(const bf16x8*)(&Pl[w][l15][32 + l4 * 8]);
#pragma unroll
        for (int dt = 0; dt < 4; ++dt) {
            bf16x8 vf0 = *(const bf16x8*)(&Vt[dt * 16 + l15][l4 * 8]);
            bf16x8 vf1 = *(const bf16x8*)(&Vt[dt * 16 + l15][32 + l4 * 8]);
            acc[dt] = __builtin_amdgcn_mfma_f32_16x16x32_bf16(pf0, vf0, acc[dt], 0, 0, 0);
            acc[dt] = __builtin_amdgcn_mfma_f32_16x16x32_bf16(pf1, vf1, acc[dt], 0, 0, 0);
        }
    }

    // ---- epilogue: reduce per-lane lrun across the 16-lane key-column group,
    //      then normalize. mrun is uniform within each group (slow-path reduce).
    float inv[4];
#pragma unroll
    for (int r = 0; r < 4; ++r) {
        float lt = lrun[r];
#pragma unroll
        for (int o = 1; o < 16; o <<= 1) lt += __shfl_xor(lt, o, 64);
        inv[r] = (lt > 0.f) ? (1.f / lt) : 0.f;
    }
    u16* op = ao + ((size_t)(bbi * 2048 + n0 + w * 16)) * 512 + h * 64;
#pragma unroll
    for (int dt = 0; dt < 4; ++dt)
#pragma unroll
        for (int r = 0; r < 4; ++r)
            op[(size_t)(l4 * 4 + r) * 512 + dt * 16 + l15] = f2bf(acc[dt][r] * inv[r]);
}

// ---------------------------------------------------------------------------
// Inputs: FLOAT32; output d_out: FLOAT32 (32 MB). 4 launches total.
// xn (bf16, 16MB) lives in d_out[0..16MB) (o_gemm overwrites all 32MB).
// ws use ~= 28 MB + 16 KB.
// ---------------------------------------------------------------------------
extern "C" void kernel_launch(void* const* d_in, const int* in_sizes, int n_in,
                              void* d_out, int out_size, void* d_ws, size_t ws_size,
                              hipStream_t stream) {
    const float* x = (const float*)d_in[0];
    const float* media = (const float*)d_in[1];
    const unsigned char* mask = (const unsigned char*)d_in[2];
    const float* ln_g = (const float*)d_in[3];
    const float* ln_b = (const float*)d_in[4];
    const float* Wq = (const float*)d_in[5];
    const float* Wkv = (const float*)d_in[6];
    const float* Wo = (const float*)d_in[7];
    float* out = (float*)d_out;

    char* w = (char*)d_ws;
    unsigned char* mask8 = (unsigned char*)w; w += 4096;
    int* idx = (int*)w;    w += 2048 * 4;
    int* cnts = (int*)w;   w += 256;
    u16* qb = (u16*)w;     w += (size_t)8192 * 512 * 2;
    u16* kvb = (u16*)w;    w += (size_t)2048 * 1024 * 2;
    u16* ao = (u16*)w;     w += (size_t)8192 * 512 * 2;
    u16* mediab = (u16*)w; w += (size_t)2048 * 1024 * 2;
    u16* wqt = (u16*)w;    w += (size_t)512 * 1024 * 2;
    u16* wkvt = (u16*)w;   w += (size_t)1024 * 1024 * 2;
    u16* wot = (u16*)w;    w += (size_t)1024 * 512 * 2;
    u16* xn = (u16*)d_out;

    prep_all<<<3841, 256, 0, stream>>>(x, media, mask, ln_g, ln_b, Wq, Wkv, Wo,
                                       xn, mediab, mask8, idx, cnts, wqt, wkvt, wot);
    qkv_gemm<<<384, 256, 0, stream>>>(xn, wqt, qb, mediab, wkvt, kvb);
    attn_mfma<<<dim3(32, 8, 4), 256, 0, stream>>>(qb, kvb, idx, cnts, ao);
    o_gemm<<<dim3(8, 64), 256, 0, stream>>>(ao, wot, out);
}

// Round 14
// 75.862 us; speedup vs baseline: 5.9589x; 1.0259x over previous
//
#include <hip/hip_runtime.h>
#include <hip/hip_bf16.h>

typedef unsigned short u16;
typedef __attribute__((ext_vector_type(4))) unsigned short u16x4;
typedef __attribute__((ext_vector_type(8))) unsigned short u16x8;
typedef __attribute__((ext_vector_type(8))) short bf16x8;
typedef __attribute__((ext_vector_type(4))) float f32x4;

#define AS1 __attribute__((address_space(1)))
#define AS3 __attribute__((address_space(3)))

__device__ __forceinline__ float b2f(u16 v) {
    return __uint_as_float(((unsigned)v) << 16);
}
__device__ __forceinline__ u16 f2bf(float f) {
    unsigned u = __float_as_uint(f);
    unsigned r = (u + 0x7fffu + ((u >> 16) & 1u)) >> 16;
    return (u16)r;
}

// ---------------------------------------------------------------------------
// prep_all: one launch for all independent preprocessing.
//   blocks [0,2048)    : LayerNorm x -> xn (bf16), 4 rows/block
//   blocks [2048,3072) : media f32 -> bf16
//   blocks [3072,3840) : weight transpose-convert (Wq,Wkv,Wo) -> (N,K) bf16
//   block  3840        : mask detect {bool8,int32,f32} + ballot-compact idx
//                        (idx padded with 0 to a multiple of 128 — KV-GEMM
//                         row tiles of 128 and attn KVBLK=64 both covered)
// ---------------------------------------------------------------------------
__global__ __launch_bounds__(256) void prep_all(
    const float* __restrict__ x, const float* __restrict__ media,
    const unsigned char* __restrict__ mask,
    const float* __restrict__ ln_g, const float* __restrict__ ln_b,
    const float* __restrict__ Wq, const float* __restrict__ Wkv,
    const float* __restrict__ Wo,
    u16* __restrict__ xn, u16* __restrict__ mediab,
    unsigned char* __restrict__ mask8, int* __restrict__ idx,
    int* __restrict__ cnts,
    u16* __restrict__ wqt, u16* __restrict__ wkvt, u16* __restrict__ wot) {
    __shared__ u16 T[64][72];
    __shared__ int c0s, c1s;
    const int bid = blockIdx.x, tid = threadIdx.x;

    if (bid < 2048) {  // ---- LayerNorm ----
        const int lane = tid & 63;
        const int row = bid * 4 + (tid >> 6);
        const float* xr = x + (size_t)row * 1024;
        float v[16];
        float sum = 0.f, sq = 0.f;
#pragma unroll
        for (int c = 0; c < 4; ++c) {
            float4 u = ((const float4*)xr)[c * 64 + lane];
            v[c * 4 + 0] = u.x; v[c * 4 + 1] = u.y; v[c * 4 + 2] = u.z; v[c * 4 + 3] = u.w;
            sum += u.x + u.y + u.z + u.w;
            sq += u.x * u.x + u.y * u.y + u.z * u.z + u.w * u.w;
        }
#pragma unroll
        for (int o = 1; o < 64; o <<= 1) {
            sum += __shfl_xor(sum, o, 64);
            sq += __shfl_xor(sq, o, 64);
        }
        float mean = sum * (1.f / 1024.f);
        float var = sq * (1.f / 1024.f) - mean * mean;
        float rs = rsqrtf(var + 1e-5f);
        u16* yr = xn + (size_t)row * 1024;
#pragma unroll
        for (int c = 0; c < 4; ++c) {
            float4 ug = ((const float4*)ln_g)[c * 64 + lane];
            float4 ub = ((const float4*)ln_b)[c * 64 + lane];
            u16x4 o;
            o[0] = f2bf((v[c * 4 + 0] - mean) * rs * ug.x + ub.x);
            o[1] = f2bf((v[c * 4 + 1] - mean) * rs * ug.y + ub.y);
            o[2] = f2bf((v[c * 4 + 2] - mean) * rs * ug.z + ub.z);
            o[3] = f2bf((v[c * 4 + 3] - mean) * rs * ug.w + ub.w);
            *(u16x4*)(yr + c * 256 + lane * 4) = o;
        }
    } else if (bid < 3072) {  // ---- media f32->bf16 ----
        int i = (bid - 2048) * 256 + tid;
        float4 a = ((const float4*)media)[i * 2];
        float4 b = ((const float4*)media)[i * 2 + 1];
        u16x8 o;
        o[0] = f2bf(a.x); o[1] = f2bf(a.y); o[2] = f2bf(a.z); o[3] = f2bf(a.w);
        o[4] = f2bf(b.x); o[5] = f2bf(b.y); o[6] = f2bf(b.z); o[7] = f2bf(b.w);
        ((u16x8*)mediab)[i] = o;
    } else if (bid < 3840) {  // ---- weight transpose-convert ----
        const int t = bid - 3072;
        const int z = t >> 8, rem = t & 255;
        const float* in; u16* out; int K, N;
        if (z == 0)      { in = Wq;  out = wqt;  K = 1024; N = 512; }
        else if (z == 1) { in = Wkv; out = wkvt; K = 1024; N = 1024; }
        else             { in = Wo;  out = wot;  K = 512;  N = 1024; }
        const int k0 = (rem >> 4) * 64, n0 = (rem & 15) * 64;
        if (k0 >= K || n0 >= N) return;
#pragma unroll
        for (int p = 0; p < 4; ++p) {
            int kr = p * 16 + (tid >> 4);
            float4 u = *(const float4*)(in + (size_t)(k0 + kr) * N + n0 + (tid & 15) * 4);
            u16x4 o4;
            o4[0] = f2bf(u.x); o4[1] = f2bf(u.y); o4[2] = f2bf(u.z); o4[3] = f2bf(u.w);
            *(u16x4*)(&T[kr][(tid & 15) * 4]) = o4;
        }
        __syncthreads();
        const int n = tid >> 2, kc = (tid & 3) * 16;
#pragma unroll
        for (int hh = 0; hh < 2; ++hh) {
            u16x8 o;
#pragma unroll
            for (int i = 0; i < 8; ++i) o[i] = T[kc + hh * 8 + i][n];
            *(u16x8*)(out + (size_t)(n0 + n) * K + k0 + kc + hh * 8) = o;
        }
    } else {  // ---- mask detect + compact ----
        if (tid == 0) { c0s = 0; c1s = 0; }
        __syncthreads();
        int a0 = 0, a1 = 0;
        for (int i = tid; i < 2048; i += 256) {
            if (mask[i]) {
                int cl = i & 3;
                if (cl == 0) a0 = 1;
                else if (cl == 1) a1 = 1;
            }
        }
        if (a0) atomicOr(&c0s, 1);
        if (a1) atomicOr(&c1s, 1);
        __syncthreads();
        int fmt = c1s ? 1 : (c0s ? 0 : 2);  // 1=bool8, 0=int32, 2=float32
        for (int e = tid; e < 2048; e += 256) {
            unsigned char v;
            if (fmt == 1)      v = (mask[e] != 0);
            else if (fmt == 0) v = (((const int*)mask)[e] != 0);
            else               v = (((const float*)mask)[e] != 0.f);
            mask8[e] = v;
        }
        __syncthreads();
        const int wv = tid >> 6, l = tid & 63;
        int off = 0;
#pragma unroll
        for (int c = 0; c < 8; ++c) {
            int key = c * 64 + l;
            bool v = mask8[wv * 512 + key] != 0;
            unsigned long long m = __ballot(v);
            int rank = __popcll(m & ((1ull << l) - 1ull));
            if (v) idx[wv * 512 + off + rank] = key;
            off += __popcll(m);
        }
        if (l == 0) cnts[wv] = off;
        int nt = (off + 127) & ~127;        // pad to 128 (KV-GEMM row tile)
        for (int p = off + l; p < nt; p += 64) idx[wv * 512 + p] = 0;
    }
}

// ---------------------------------------------------------------------------
// GEMM tile body with global_load_lds staging + XOR-swizzled LDS.
// C(128x128 tile) = A(MxK) @ Bt(NxK)^T, BK=64, 4 waves.
// GATHER=1: A row g is A[ridx[row0+g]] (per-lane global source — legal for
// global_load_lds; only the LDS dest must be linear).
// ---------------------------------------------------------------------------
template <int OUTF32, int GATHER>
__device__ __forceinline__ void gemm_tile_g(u16* As, u16* Bs,
                                            const u16* __restrict__ A,
                                            const u16* __restrict__ Bt,
                                            void* __restrict__ Cv,
                                            int N, int K, int row0, int col0,
                                            float scale,
                                            const int* __restrict__ ridx) {
    const int tid = threadIdx.x;
    const int l = tid & 63, w = tid >> 6;
    const int l15 = l & 15, l4 = l >> 4;
    const int wm = w >> 1, wn = w & 1;
    const int lr = l >> 3;                 // row-within-8 for staging
    const int cs = ((l & 7) ^ lr) * 8;     // pre-swizzled source slot (elems)

    // per-thread A source rows (loop-invariant over k0)
    int arow[4];
#pragma unroll
    for (int i = 0; i < 4; ++i) {
        int g = w * 32 + i * 8 + lr;
        arow[i] = GATHER ? ridx[row0 + g] : (row0 + g);
    }

    f32x4 zero = {0.f, 0.f, 0.f, 0.f};
    f32x4 acc[4][4];
#pragma unroll
    for (int i = 0; i < 4; ++i)
#pragma unroll
        for (int j = 0; j < 4; ++j) acc[i][j] = zero;

    const int rsw = l15 & 7;               // row&7 for all fragment rows

    for (int k0 = 0; k0 < K; k0 += 64) {
        __syncthreads();
#pragma unroll
        for (int i = 0; i < 4; ++i) {
            int r = w * 32 + i * 8;        // wave-uniform 8-row group
            __builtin_amdgcn_global_load_lds(
                (const AS1 void*)(A + (size_t)arow[i] * K + k0 + cs),
                (AS3 void*)(As + r * 64), 16, 0, 0);
            __builtin_amdgcn_global_load_lds(
                (const AS1 void*)(Bt + (size_t)(col0 + r + lr) * K + k0 + cs),
                (AS3 void*)(Bs + r * 64), 16, 0, 0);
        }
        __syncthreads();
#pragma unroll
        for (int h = 0; h < 2; ++h) {      // two K=32 sub-steps
            bf16x8 aF[4], bF[4];
#pragma unroll
            for (int m = 0; m < 4; ++m) {
                int s = (h * 4 + l4) ^ rsw;             // swizzled slot
                aF[m] = *(const bf16x8*)(As + (wm * 64 + m * 16 + l15) * 64 + s * 8);
                bF[m] = *(const bf16x8*)(Bs + (wn * 64 + m * 16 + l15) * 64 + s * 8);
            }
#pragma unroll
            for (int m = 0; m < 4; ++m)
#pragma unroll
                for (int n = 0; n < 4; ++n)
                    acc[m][n] = __builtin_amdgcn_mfma_f32_16x16x32_bf16(aF[m], bF[n], acc[m][n], 0, 0, 0);
        }
    }
#pragma unroll
    for (int m = 0; m < 4; ++m)
#pragma unroll
        for (int n = 0; n < 4; ++n) {
            int row = row0 + wm * 64 + m * 16 + l4 * 4;
            int col = col0 + wn * 64 + n * 16 + l15;
#pragma unroll
            for (int r = 0; r < 4; ++r) {
                float vv = acc[m][n][r] * scale;
                if (OUTF32)
                    ((float*)Cv)[(size_t)(row + r) * N + col] = vv;
                else
                    ((u16*)Cv)[(size_t)(row + r) * N + col] = f2bf(vv);
            }
        }
}

// ---------------------------------------------------------------------------
// Merged Q + compacted-KV projection GEMM.
//   blocks [0,256)   : qb = (xn @ Wq) * 0.125   (8192x512, K=1024)
//   blocks [256,384) : kvb[b][j] = mediab[b][idx[b][j]] @ Wkv for the ~cnt
//                      valid keys only (50% masked -> ~half the KV FLOPs);
//                      row tiles beyond the 128-padded count exit early.
// ---------------------------------------------------------------------------
__global__ __launch_bounds__(256, 2) void qkv_gemm(const u16* __restrict__ xn,
                                                   const u16* __restrict__ wqt,
                                                   u16* __restrict__ qb,
                                                   const u16* __restrict__ mediab,
                                                   const u16* __restrict__ wkvt,
                                                   u16* __restrict__ kvb,
                                                   const int* __restrict__ idx,
                                                   const int* __restrict__ cnts) {
    __shared__ u16 As[128 * 64];
    __shared__ u16 Bs[128 * 64];
    const int b = blockIdx.x;
    if (b < 256) {
        gemm_tile_g<0, 0>(As, Bs, xn, wqt, (void*)qb, 512, 1024,
                          (b >> 2) * 128, (b & 3) * 128, 0.125f, nullptr);
    } else {
        const int t = b - 256;
        const int bbi = t >> 5, rem = t & 31;
        const int row0 = (rem >> 3) * 128, col0 = (rem & 7) * 128;
        const int nt128 = (cnts[bbi] + 127) & ~127;
        if (row0 >= nt128) return;
        gemm_tile_g<0, 1>(As, Bs, mediab + (size_t)bbi * 512 * 1024, wkvt,
                          (void*)(kvb + (size_t)bbi * 512 * 1024), 1024, 1024,
                          row0, col0, 1.f, idx + bbi * 512);
    }
}

// ---------------------------------------------------------------------------
// Output projection: out = ao @ Wo  (8192x1024, K=512), f32 store.
// ---------------------------------------------------------------------------
__global__ __launch_bounds__(256, 2) void o_gemm(const u16* __restrict__ ao,
                                                 const u16* __restrict__ wot,
                                                 float* __restrict__ out) {
    __shared__ u16 As[128 * 64];
    __shared__ u16 Bs[128 * 64];
    gemm_tile_g<1, 0>(As, Bs, ao, wot, (void*)out, 1024, 512,
                      (int)blockIdx.y * 128, (int)blockIdx.x * 128, 1.f, nullptr);
}

// ---------------------------------------------------------------------------
// MFMA flash attention over PRE-COMPACTED contiguous K/V. Block = 4 waves,
// QBLK=64 (16 q-rows/wave), KVBLK=64. Grid (32, 8 heads, 4 batch).
// kvb rows are already compacted (KV-GEMM gathered) -> no index LDS, no
// gather in the hot loop. Pad rows (j >= cnt) hold valid key-0 projections,
// masked by mv (expf(-3e38 - mn) == 0).
// Defer-max (T13) + per-lane lrun partial (epilogue-reduced).
// ---------------------------------------------------------------------------
__global__ __launch_bounds__(256) void attn_mfma(const u16* __restrict__ qb,
                                                 const u16* __restrict__ kvb,
                                                 const int* __restrict__ cnts,
                                                 u16* __restrict__ ao) {
    __shared__ u16 Ks[64][72];      // K tile [j][d]
    __shared__ u16 Vt[64][72];      // V^T tile [d][j]
    __shared__ u16 Pl[4][16][72];   // per-wave P [q][j]
    const int tid = threadIdx.x;
    const int l = tid & 63, w = tid >> 6;
    const int l15 = l & 15, l4 = l >> 4;
    const int h = blockIdx.y, bbi = blockIdx.z;
    const int n0 = blockIdx.x * 64;
    const int cnt = cnts[bbi];

    const u16* qp = qb + ((size_t)(bbi * 2048 + n0 + w * 16 + l15)) * 512 + h * 64;
    const bf16x8 qf0 = *(const bf16x8*)(qp + l4 * 8);
    const bf16x8 qf1 = *(const bf16x8*)(qp + 32 + l4 * 8);

    const f32x4 zero = {0.f, 0.f, 0.f, 0.f};
    f32x4 acc[4];
#pragma unroll
    for (int dt = 0; dt < 4; ++dt) acc[dt] = zero;
    float mrun[4] = {-3.0e38f, -3.0e38f, -3.0e38f, -3.0e38f};
    float lrun[4] = {0.f, 0.f, 0.f, 0.f};   // per-lane partial denominator

    const int kj = tid >> 3, kd = (tid & 7) * 8;
    const int vj = tid & 63, vd = (tid >> 6) * 16;
    const u16* kbase = kvb + ((size_t)bbi * 512) * 1024 + h * 64;

    for (int j0 = 0; j0 < cnt; j0 += 64) {
        __syncthreads();
#pragma unroll
        for (int p = 0; p < 2; ++p) {
            int r = kj + p * 32;
            u16x8 kv_ = *(const u16x8*)(kbase + (size_t)(j0 + r) * 1024 + kd);
            *(u16x8*)(&Ks[r][kd]) = kv_;
        }
        {
#pragma unroll
            for (int p = 0; p < 2; ++p) {
                u16x8 vv = *(const u16x8*)(kbase + (size_t)(j0 + vj) * 1024 + 512 + vd + p * 8);
#pragma unroll
                for (int i = 0; i < 8; ++i) Vt[vd + p * 8 + i][vj] = vv[i];
            }
        }
        __syncthreads();

        // ---- S = Q K^T (16q x 64j), 8 MFMA ----
        f32x4 s[4];
        float mv[4];
#pragma unroll
        for (int jt = 0; jt < 4; ++jt) {
            bf16x8 kf0 = *(const bf16x8*)(&Ks[jt * 16 + l15][l4 * 8]);
            bf16x8 kf1 = *(const bf16x8*)(&Ks[jt * 16 + l15][32 + l4 * 8]);
            s[jt] = __builtin_amdgcn_mfma_f32_16x16x32_bf16(qf0, kf0, zero, 0, 0, 0);
            s[jt] = __builtin_amdgcn_mfma_f32_16x16x32_bf16(qf1, kf1, s[jt], 0, 0, 0);
            mv[jt] = (j0 + jt * 16 + l15 < cnt) ? 0.f : -3.0e38f;
        }

        // ---- defer-max test (one ballot for the whole wave) ----
        float sv[4][4];   // [r][jt]
        float pmax[4];
        bool cond = true;
#pragma unroll
        for (int r = 0; r < 4; ++r) {
#pragma unroll
            for (int jt = 0; jt < 4; ++jt) sv[r][jt] = s[jt][r] + mv[jt];
            pmax[r] = fmaxf(fmaxf(sv[r][0], sv[r][1]), fmaxf(sv[r][2], sv[r][3]));
            cond = cond && (pmax[r] <= mrun[r] + 8.f);
        }
        if (__all(cond)) {
            // ---- fast path: no reduction, no rescale ----
#pragma unroll
            for (int r = 0; r < 4; ++r) {
                float p0 = __expf(sv[r][0] - mrun[r]);
                float p1 = __expf(sv[r][1] - mrun[r]);
                float p2 = __expf(sv[r][2] - mrun[r]);
                float p3 = __expf(sv[r][3] - mrun[r]);
                lrun[r] += (p0 + p1) + (p2 + p3);
                Pl[w][l4 * 4 + r][l15] = f2bf(p0);
                Pl[w][l4 * 4 + r][16 + l15] = f2bf(p1);
                Pl[w][l4 * 4 + r][32 + l15] = f2bf(p2);
                Pl[w][l4 * 4 + r][48 + l15] = f2bf(p3);
            }
        } else {
            // ---- slow path: full online-softmax update ----
#pragma unroll
            for (int r = 0; r < 4; ++r) {
                float tmax = pmax[r];
#pragma unroll
                for (int o = 1; o < 16; o <<= 1) tmax = fmaxf(tmax, __shfl_xor(tmax, o, 64));
                float mn = fmaxf(mrun[r], tmax);
                float corr = __expf(mrun[r] - mn);
                mrun[r] = mn;
                float p0 = __expf(sv[r][0] - mn);
                float p1 = __expf(sv[r][1] - mn);
                float p2 = __expf(sv[r][2] - mn);
                float p3 = __expf(sv[r][3] - mn);
                lrun[r] = lrun[r] * corr + (p0 + p1) + (p2 + p3);
#pragma unroll
                for (int dt = 0; dt < 4; ++dt) acc[dt][r] *= corr;
                Pl[w][l4 * 4 + r][l15] = f2bf(p0);
                Pl[w][l4 * 4 + r][16 + l15] = f2bf(p1);
                Pl[w][l4 * 4 + r][32 + l15] = f2bf(p2);
                Pl[w][l4 * 4 + r][48 + l15] = f2bf(p3);
            }
        }
        // ---- O += P V (8 MFMA) ----
        bf16x8 pf0 = *(const bf16x8*)(&Pl[w][l15][l4 * 8]);
        bf16x8 pf1 = *(const bf16x8*)(&Pl[w][l15][32 + l4 * 8]);
#pragma unroll
        for (int dt = 0; dt < 4; ++dt) {
            bf16x8 vf0 = *(const bf16x8*)(&Vt[dt * 16 + l15][l4 * 8]);
            bf16x8 vf1 = *(const bf16x8*)(&Vt[dt * 16 + l15][32 + l4 * 8]);
            acc[dt] = __builtin_amdgcn_mfma_f32_16x16x32_bf16(pf0, vf0, acc[dt], 0, 0, 0);
            acc[dt] = __builtin_amdgcn_mfma_f32_16x16x32_bf16(pf1, vf1, acc[dt], 0, 0, 0);
        }
    }

    // ---- epilogue: reduce per-lane lrun across the 16-lane key-column group
    float inv[4];
#pragma unroll
    for (int r = 0; r < 4; ++r) {
        float lt = lrun[r];
#pragma unroll
        for (int o = 1; o < 16; o <<= 1) lt += __shfl_xor(lt, o, 64);
        inv[r] = (lt > 0.f) ? (1.f / lt) : 0.f;
    }
    u16* op = ao + ((size_t)(bbi * 2048 + n0 + w * 16)) * 512 + h * 64;
#pragma unroll
    for (int dt = 0; dt < 4; ++dt)
#pragma unroll
        for (int r = 0; r < 4; ++r)
            op[(size_t)(l4 * 4 + r) * 512 + dt * 16 + l15] = f2bf(acc[dt][r] * inv[r]);
}

// ---------------------------------------------------------------------------
// Inputs: FLOAT32; output d_out: FLOAT32 (32 MB). 4 launches total.
// xn (bf16, 16MB) lives in d_out[0..16MB) (o_gemm overwrites all 32MB).
// ws use ~= 28 MB + 16 KB.
// ---------------------------------------------------------------------------
extern "C" void kernel_launch(void* const* d_in, const int* in_sizes, int n_in,
                              void* d_out, int out_size, void* d_ws, size_t ws_size,
                              hipStream_t stream) {
    const float* x = (const float*)d_in[0];
    const float* media = (const float*)d_in[1];
    const unsigned char* mask = (const unsigned char*)d_in[2];
    const float* ln_g = (const float*)d_in[3];
    const float* ln_b = (const float*)d_in[4];
    const float* Wq = (const float*)d_in[5];
    const float* Wkv = (const float*)d_in[6];
    const float* Wo = (const float*)d_in[7];
    float* out = (float*)d_out;

    char* w = (char*)d_ws;
    unsigned char* mask8 = (unsigned char*)w; w += 4096;
    int* idx = (int*)w;    w += 2048 * 4;
    int* cnts = (int*)w;   w += 256;
    u16* qb = (u16*)w;     w += (size_t)8192 * 512 * 2;
    u16* kvb = (u16*)w;    w += (size_t)2048 * 1024 * 2;
    u16* ao = (u16*)w;     w += (size_t)8192 * 512 * 2;
    u16* mediab = (u16*)w; w += (size_t)2048 * 1024 * 2;
    u16* wqt = (u16*)w;    w += (size_t)512 * 1024 * 2;
    u16* wkvt = (u16*)w;   w += (size_t)1024 * 1024 * 2;
    u16* wot = (u16*)w;    w += (size_t)1024 * 512 * 2;
    u16* xn = (u16*)d_out;

    prep_all<<<3841, 256, 0, stream>>>(x, media, mask, ln_g, ln_b, Wq, Wkv, Wo,
                                       xn, mediab, mask8, idx, cnts, wqt, wkvt, wot);
    qkv_gemm<<<384, 256, 0, stream>>>(xn, wqt, qb, mediab, wkvt, kvb, idx, cnts);
    attn_mfma<<<dim3(32, 8, 4), 256, 0, stream>>>(qb, kvb, cnts, ao);
    o_gemm<<<dim3(8, 64), 256, 0, stream>>>(ao, wot, out);
}